// Round 1
// baseline (134.472 us; speedup 1.0000x reference)
//
#include <hip/hip_runtime.h>
#include <hip/hip_bf16.h>

typedef short short8 __attribute__((ext_vector_type(8)));
typedef float f32x4 __attribute__((ext_vector_type(4)));
typedef const void __attribute__((address_space(1))) as1_void;
typedef void __attribute__((address_space(3))) as3_void;

#define TWO_PI_OVER_4096 0.00153398078788564123f

// ---------------------------------------------------------------------------
// Basis generation: F2 [640][4096] bf16  (rows 0..256 = cos, 257..513 = -sin,
// 514..639 = 0).   Gm [4096][576] bf16 (cols 0..256 = cos, 257..513 = -sin,
// 514..575 = 0).
// ---------------------------------------------------------------------------
__global__ __launch_bounds__(256) void gen_f2_kernel(__hip_bfloat16* F2) {
  unsigned gid = blockIdx.x * 256u + threadIdx.x;   // < 640*4096
  int mm = gid >> 12;
  int n  = gid & 4095;
  float v = 0.f;
  if (mm < 257)      v =  cosf((float)((mm * n) & 4095) * TWO_PI_OVER_4096);
  else if (mm < 514) v = -sinf((float)(((mm - 257) * n) & 4095) * TWO_PI_OVER_4096);
  F2[gid] = __float2bfloat16(v);
}

__global__ __launch_bounds__(256) void gen_gm_kernel(__hip_bfloat16* Gm) {
  int n = blockIdx.x;   // 0..4095
  for (int kk = threadIdx.x; kk < 576; kk += 256) {
    float v = 0.f;
    if (kk < 257)      v =  cosf((float)((kk * n) & 4095) * TWO_PI_OVER_4096);
    else if (kk < 514) v = -sinf((float)(((kk - 257) * n) & 4095) * TWO_PI_OVER_4096);
    Gm[(size_t)n * 576 + kk] = __float2bfloat16(v);
  }
}

// ---------------------------------------------------------------------------
// x (f32 [32][4096][64]) -> X2T (bf16 [2048][4096]),  X2T[b*64+i][n] = x[b][n][i]
// ---------------------------------------------------------------------------
__global__ __launch_bounds__(256) void transpose_x_kernel(const float* __restrict__ x,
                                                          __hip_bfloat16* __restrict__ X2T) {
  int nt = blockIdx.x;   // 0..63
  int b  = blockIdx.y;   // 0..31
  int n0 = nt * 64;
  __shared__ float tile[64][65];
#pragma unroll
  for (int it = 0; it < 4; ++it) {
    int c = it * 256 + threadIdx.x;       // 0..1023 float4 chunks
    int r = c >> 4, i4 = (c & 15) * 4;
    float4 v = *(const float4*)&x[((size_t)b * 4096 + n0 + r) * 64 + i4];
    tile[r][i4 + 0] = v.x; tile[r][i4 + 1] = v.y;
    tile[r][i4 + 2] = v.z; tile[r][i4 + 3] = v.w;
  }
  __syncthreads();
#pragma unroll
  for (int it = 0; it < 2; ++it) {
    int c = it * 256 + threadIdx.x;       // 0..511
    int i = c & 63, r0 = (c >> 6) * 8;
    union { short8 v; unsigned short u[8]; } pk;
#pragma unroll
    for (int j = 0; j < 8; ++j) {
      __hip_bfloat16 h = __float2bfloat16(tile[r0 + j][i]);
      pk.u[j] = *(unsigned short*)&h;
    }
    *(short8*)&X2T[((size_t)b * 64 + i) * 4096 + n0 + r0] = pk.v;
  }
}

// ---------------------------------------------------------------------------
// S[b][m] = (t_emb @ dense_real + i t_emb @ dense_imag) * c_m / 4096
// ---------------------------------------------------------------------------
__global__ __launch_bounds__(256) void t_mod_kernel(const float* __restrict__ t_emb,
                                                    const float* __restrict__ dr,
                                                    const float* __restrict__ di,
                                                    float* __restrict__ Sr,
                                                    float* __restrict__ Si) {
  int b = blockIdx.x;
  __shared__ float te[256];
  te[threadIdx.x] = t_emb[b * 256 + threadIdx.x];
  __syncthreads();
  for (int m = threadIdx.x; m < 257; m += 256) {
    float ar = 0.f, ai = 0.f;
    for (int t = 0; t < 256; ++t) {
      float e = te[t];
      ar += e * dr[t * 257 + m];
      ai += e * di[t * 257 + m];
    }
    float c = (m == 0 ? 1.0f : 2.0f) * (1.0f / 4096.0f);
    Sr[b * 257 + m] = ar * c;
    Si[b * 257 + m] = ai * c;
  }
}

// ---------------------------------------------------------------------------
// Shared MFMA GEMM core: C(128x128) += A[m0:+128, k0:+64*ksteps] *
// B[n0:+128, ...]^T where A,B are row-major [rows][K] bf16.
// m97 structure: global_load_lds(16B) staging, 2-barrier K-loop,
// T2 chunk-XOR swizzle (pre-swizzled global source).
// ---------------------------------------------------------------------------
__device__ __forceinline__ void gemm_core(const __hip_bfloat16* __restrict__ A, int lda, int m0,
                                          const __hip_bfloat16* __restrict__ B, int ldb, int n0,
                                          int k0, int ksteps,
                                          __hip_bfloat16* As, __hip_bfloat16* Bs,
                                          f32x4 acc[4][4]) {
  const int tid  = threadIdx.x;
  const int lane = tid & 63;
  const int wv   = tid >> 6;
  const int wr   = (wv >> 1) * 64;
  const int wc   = (wv & 1) * 64;
  const int fr   = lane & 15;
  const int fq   = lane >> 4;

  for (int ks = 0; ks < ksteps; ++ks) {
    int kt = k0 + ks * 64;
    // stage A and B tiles: 1024 16B-chunks each, LDS linear, source pre-swizzled
#pragma unroll
    for (int j = 0; j < 4; ++j) {
      int c   = j * 256 + tid;           // 0..1023
      int row = c >> 3;
      int chg = (c & 7) ^ (row & 7);     // swizzled source chunk
      const __hip_bfloat16* ga = A + (size_t)(m0 + row) * lda + kt + chg * 8;
      const __hip_bfloat16* gb = B + (size_t)(n0 + row) * ldb + kt + chg * 8;
      __hip_bfloat16* la = As + (size_t)(j * 256 + (tid & 192)) * 8;
      __hip_bfloat16* lb = Bs + (size_t)(j * 256 + (tid & 192)) * 8;
      __builtin_amdgcn_global_load_lds((as1_void*)ga, (as3_void*)la, 16, 0, 0);
      __builtin_amdgcn_global_load_lds((as1_void*)gb, (as3_void*)lb, 16, 0, 0);
    }
    __syncthreads();
#pragma unroll
    for (int kk = 0; kk < 2; ++kk) {
      short8 av[4], bv[4];
#pragma unroll
      for (int m = 0; m < 4; ++m) {
        int row  = wr + m * 16 + fr;
        int slot = (fq + kk * 4) ^ (row & 7);
        av[m] = *(const short8*)(As + row * 64 + slot * 8);
      }
#pragma unroll
      for (int n = 0; n < 4; ++n) {
        int row  = wc + n * 16 + fr;
        int slot = (fq + kk * 4) ^ (row & 7);
        bv[n] = *(const short8*)(Bs + row * 64 + slot * 8);
      }
#pragma unroll
      for (int m = 0; m < 4; ++m)
#pragma unroll
        for (int n = 0; n < 4; ++n)
          acc[m][n] = __builtin_amdgcn_mfma_f32_16x16x32_bf16(av[m], bv[n], acc[m][n], 0, 0, 0);
    }
    __syncthreads();
  }
}

// GEMM1: C1[z][mm][bi] (fp32 split-K partials) = F2 @ X2T^T
__global__ __launch_bounds__(256) void gemm1_kernel(const __hip_bfloat16* __restrict__ F2,
                                                    const __hip_bfloat16* __restrict__ X2T,
                                                    float* __restrict__ C1, int kchunk) {
  __shared__ __hip_bfloat16 As[128 * 64];
  __shared__ __hip_bfloat16 Bs[128 * 64];
  int n0 = blockIdx.x * 128;
  int m0 = blockIdx.y * 128;
  int k0 = blockIdx.z * kchunk;
  f32x4 acc[4][4];
#pragma unroll
  for (int m = 0; m < 4; ++m)
#pragma unroll
    for (int n = 0; n < 4; ++n)
#pragma unroll
      for (int r = 0; r < 4; ++r) acc[m][n][r] = 0.f;

  gemm_core(F2, 4096, m0, X2T, 4096, n0, k0, kchunk >> 6, As, Bs, acc);

  const int lane = threadIdx.x & 63;
  const int wv   = threadIdx.x >> 6;
  const int wr   = (wv >> 1) * 64, wc = (wv & 1) * 64;
  const int fr   = lane & 15, fq = lane >> 4;
  float* P = C1 + (size_t)blockIdx.z * (640 * 2048);
#pragma unroll
  for (int m = 0; m < 4; ++m)
#pragma unroll
    for (int n = 0; n < 4; ++n)
#pragma unroll
      for (int j = 0; j < 4; ++j) {
        int row = m0 + wr + m * 16 + fq * 4 + j;
        int col = n0 + wc + n * 16 + fr;
        P[(size_t)row * 2048 + col] = acc[m][n][j];
      }
}

// reduce split-K partials -> X3 [514][2048] fp32
__global__ __launch_bounds__(256) void reduce1_kernel(const float* __restrict__ C1,
                                                      float* __restrict__ X3, int splitk) {
  size_t g4 = ((size_t)blockIdx.x * 256 + threadIdx.x) * 4;   // < 514*2048
  float4 s = {0.f, 0.f, 0.f, 0.f};
  for (int j = 0; j < splitk; ++j) {
    float4 v = *(const float4*)&C1[(size_t)j * (640 * 2048) + g4];
    s.x += v.x; s.y += v.y; s.z += v.z; s.w += v.w;
  }
  *(float4*)&X3[g4] = s;
}

// ---------------------------------------------------------------------------
// Mode mix: per k: Y = (X . W) * S, store Y2 [514][2048] bf16 (rows k / 257+k)
// ---------------------------------------------------------------------------
__global__ __launch_bounds__(256) void mix_kernel(const float* __restrict__ X3,
                                                  const float* __restrict__ Wr,
                                                  const float* __restrict__ Wi,
                                                  const float* __restrict__ Sr,
                                                  const float* __restrict__ Si,
                                                  __hip_bfloat16* __restrict__ Y2) {
  int k = blockIdx.x;   // 0..256
  __shared__ float xr[2048];
  __shared__ float xi[2048];
  for (int c = threadIdx.x; c < 2048; c += 256) {
    xr[c] = X3[(size_t)k * 2048 + c];
    xi[c] = X3[(size_t)(257 + k) * 2048 + c];
  }
  __syncthreads();
  int o  = threadIdx.x & 63;
  int bs = threadIdx.x >> 6;   // 0..3 -> b = bs*8 + j
  const float* wr = Wr + (size_t)k * 4096;  // [i][o]
  const float* wi = Wi + (size_t)k * 4096;
  float pr[8], pi[8];
#pragma unroll
  for (int j = 0; j < 8; ++j) { pr[j] = 0.f; pi[j] = 0.f; }
  for (int i = 0; i < 64; ++i) {
    float wrv = wr[i * 64 + o], wiv = wi[i * 64 + o];
#pragma unroll
    for (int j = 0; j < 8; ++j) {
      int b = bs * 8 + j;
      float xrv = xr[b * 64 + i], xiv = xi[b * 64 + i];
      pr[j] += xrv * wrv - xiv * wiv;
      pi[j] += xrv * wiv + xiv * wrv;
    }
  }
#pragma unroll
  for (int j = 0; j < 8; ++j) {
    int b = bs * 8 + j;
    float sr = Sr[b * 257 + k], si = Si[b * 257 + k];
    float yr = pr[j] * sr - pi[j] * si;
    float yi = pr[j] * si + pi[j] * sr;
    Y2[(size_t)k * 2048 + b * 64 + o]         = __float2bfloat16(yr);
    Y2[(size_t)(257 + k) * 2048 + b * 64 + o] = __float2bfloat16(yi);
  }
}

// Y2 [514][2048] -> Y2T [2048][576] (cols >= 514 zero-filled)
__global__ __launch_bounds__(256) void transpose_y_kernel(const __hip_bfloat16* __restrict__ Y2,
                                                          __hip_bfloat16* __restrict__ Y2T) {
  int kt = blockIdx.x;   // 0..8
  int bt = blockIdx.y;   // 0..31
  int k0 = kt * 64, b0 = bt * 64;
  __shared__ unsigned short tile[64][65];
  const unsigned short* src = (const unsigned short*)Y2;
#pragma unroll
  for (int it = 0; it < 16; ++it) {
    int c = it * 256 + threadIdx.x;
    int r = c >> 6, cc = c & 63;
    tile[r][cc] = (k0 + r < 514) ? src[(size_t)(k0 + r) * 2048 + b0 + cc] : (unsigned short)0;
  }
  __syncthreads();
  unsigned short* dst = (unsigned short*)Y2T;
#pragma unroll
  for (int it = 0; it < 16; ++it) {
    int c = it * 256 + threadIdx.x;
    int orow = c >> 6, ocol = c & 63;    // orow = bo, ocol = kk
    dst[(size_t)(b0 + orow) * 576 + k0 + ocol] = tile[ocol][orow];
  }
}

// GEMM2: out[b][n][o] = Gm[n][:] . Y2T[bo][:]
__global__ __launch_bounds__(256) void gemm2_kernel(const __hip_bfloat16* __restrict__ Gm,
                                                    const __hip_bfloat16* __restrict__ Y2T,
                                                    float* __restrict__ out) {
  __shared__ __hip_bfloat16 As[128 * 64];
  __shared__ __hip_bfloat16 Bs[128 * 64];
  int n0 = blockIdx.x * 128;   // bo
  int m0 = blockIdx.y * 128;   // n (time)
  f32x4 acc[4][4];
#pragma unroll
  for (int m = 0; m < 4; ++m)
#pragma unroll
    for (int n = 0; n < 4; ++n)
#pragma unroll
      for (int r = 0; r < 4; ++r) acc[m][n][r] = 0.f;

  gemm_core(Gm, 576, m0, Y2T, 576, n0, 0, 9, As, Bs, acc);

  const int lane = threadIdx.x & 63;
  const int wv   = threadIdx.x >> 6;
  const int wr   = (wv >> 1) * 64, wc = (wv & 1) * 64;
  const int fr   = lane & 15, fq = lane >> 4;
#pragma unroll
  for (int m = 0; m < 4; ++m)
#pragma unroll
    for (int n = 0; n < 4; ++n)
#pragma unroll
      for (int j = 0; j < 4; ++j) {
        int row = m0 + wr + m * 16 + fq * 4 + j;   // n index
        int col = n0 + wc + n * 16 + fr;           // bo index
        int b = col >> 6, o = col & 63;
        out[((size_t)b * 4096 + row) * 64 + o] = acc[m][n][j];
      }
}

// ---------------------------------------------------------------------------
extern "C" void kernel_launch(void* const* d_in, const int* in_sizes, int n_in,
                              void* d_out, int out_size, void* d_ws, size_t ws_size,
                              hipStream_t stream) {
  const float* x  = (const float*)d_in[0];   // (32,4096,64)
  const float* te = (const float*)d_in[1];   // (32,256)
  const float* wr = (const float*)d_in[2];   // (257,64,64)
  const float* wi = (const float*)d_in[3];
  const float* dr = (const float*)d_in[4];   // (256,257)
  const float* di = (const float*)d_in[5];
  float* out = (float*)d_out;

  char* p = (char*)d_ws;
  auto alloc = [&](size_t bytes) -> char* {
    char* r = p;
    p += (bytes + 255) & ~(size_t)255;
    return r;
  };
  __hip_bfloat16* F2  = (__hip_bfloat16*)alloc(640ull * 4096 * 2);
  __hip_bfloat16* Gm  = (__hip_bfloat16*)alloc(4096ull * 576 * 2);
  __hip_bfloat16* X2T = (__hip_bfloat16*)alloc(2048ull * 4096 * 2);
  float* Sr = (float*)alloc(32 * 257 * 4);
  float* Si = (float*)alloc(32 * 257 * 4);
  __hip_bfloat16* Y2  = (__hip_bfloat16*)alloc(514ull * 2048 * 2);
  __hip_bfloat16* Y2T = (__hip_bfloat16*)alloc(2048ull * 576 * 2);
  float* X3 = (float*)alloc(514ull * 2048 * 4);
  size_t fixed = (size_t)(p - (char*)d_ws);

  int splitk = 1;
  if (ws_size >= fixed + 8ull * 640 * 2048 * 4)      splitk = 8;
  else if (ws_size >= fixed + 4ull * 640 * 2048 * 4) splitk = 4;
  else if (ws_size >= fixed + 2ull * 640 * 2048 * 4) splitk = 2;
  float* C1 = (float*)alloc((size_t)splitk * 640 * 2048 * 4);
  int kchunk = 4096 / splitk;

  gen_f2_kernel<<<10240, 256, 0, stream>>>(F2);
  gen_gm_kernel<<<4096, 256, 0, stream>>>(Gm);
  transpose_x_kernel<<<dim3(64, 32), 256, 0, stream>>>(x, X2T);
  t_mod_kernel<<<32, 256, 0, stream>>>(te, dr, di, Sr, Si);
  gemm1_kernel<<<dim3(16, 5, splitk), 256, 0, stream>>>(F2, X2T, C1, kchunk);
  reduce1_kernel<<<1028, 256, 0, stream>>>(C1, X3, splitk);
  mix_kernel<<<257, 256, 0, stream>>>(X3, wr, wi, Sr, Si, Y2);
  transpose_y_kernel<<<dim3(9, 32), 256, 0, stream>>>(Y2, Y2T);
  gemm2_kernel<<<dim3(16, 32), 256, 0, stream>>>(Gm, Y2T, out);
}

// Round 2
// 126.362 us; speedup vs baseline: 1.0642x; 1.0642x over previous
//
#include <hip/hip_runtime.h>
#include <hip/hip_bf16.h>

typedef short short8 __attribute__((ext_vector_type(8)));
typedef float f32x4 __attribute__((ext_vector_type(4)));
typedef const void __attribute__((address_space(1))) as1_void;
typedef void __attribute__((address_space(3))) as3_void;

// hardware trig: input in revolutions (D = sin/cos(S0 * 2pi)), already in [0,1)
__device__ __forceinline__ float sin_rev(float r) {
  float o; asm("v_sin_f32 %0, %1" : "=v"(o) : "v"(r)); return o;
}
__device__ __forceinline__ float cos_rev(float r) {
  float o; asm("v_cos_f32 %0, %1" : "=v"(o) : "v"(r)); return o;
}

#define INV4096 0.000244140625f

// ---------------------------------------------------------------------------
// Basis generation: F2 [640][4096] bf16  (rows 0..256 = cos, 257..513 = -sin,
// 514..639 = 0).   Gm [4096][576] bf16 (cols 0..256 = cos, 257..513 = -sin,
// 514..575 = 0).
// ---------------------------------------------------------------------------
__global__ __launch_bounds__(256) void gen_f2_kernel(__hip_bfloat16* F2) {
  unsigned gid = blockIdx.x * 256u + threadIdx.x;   // < 640*4096
  int mm = gid >> 12;
  int n  = gid & 4095;
  float v = 0.f;
  if (mm < 257)      v =  cos_rev((float)((mm * n) & 4095) * INV4096);
  else if (mm < 514) v = -sin_rev((float)(((mm - 257) * n) & 4095) * INV4096);
  F2[gid] = __float2bfloat16(v);
}

__global__ __launch_bounds__(256) void gen_gm_kernel(__hip_bfloat16* Gm) {
  int n = blockIdx.x;   // 0..4095
  for (int kk = threadIdx.x; kk < 576; kk += 256) {
    float v = 0.f;
    if (kk < 257)      v =  cos_rev((float)((kk * n) & 4095) * INV4096);
    else if (kk < 514) v = -sin_rev((float)(((kk - 257) * n) & 4095) * INV4096);
    Gm[(size_t)n * 576 + kk] = __float2bfloat16(v);
  }
}

// ---------------------------------------------------------------------------
// x (f32 [32][4096][64]) -> X2T (bf16 [2048][4096]),  X2T[b*64+i][n] = x[b][n][i]
// ---------------------------------------------------------------------------
__global__ __launch_bounds__(256) void transpose_x_kernel(const float* __restrict__ x,
                                                          __hip_bfloat16* __restrict__ X2T) {
  int nt = blockIdx.x;   // 0..63
  int b  = blockIdx.y;   // 0..31
  int n0 = nt * 64;
  __shared__ float tile[64][65];
#pragma unroll
  for (int it = 0; it < 4; ++it) {
    int c = it * 256 + threadIdx.x;       // 0..1023 float4 chunks
    int r = c >> 4, i4 = (c & 15) * 4;
    float4 v = *(const float4*)&x[((size_t)b * 4096 + n0 + r) * 64 + i4];
    tile[r][i4 + 0] = v.x; tile[r][i4 + 1] = v.y;
    tile[r][i4 + 2] = v.z; tile[r][i4 + 3] = v.w;
  }
  __syncthreads();
#pragma unroll
  for (int it = 0; it < 2; ++it) {
    int c = it * 256 + threadIdx.x;       // 0..511
    int i = c & 63, r0 = (c >> 6) * 8;
    union { short8 v; unsigned short u[8]; } pk;
#pragma unroll
    for (int j = 0; j < 8; ++j) {
      __hip_bfloat16 h = __float2bfloat16(tile[r0 + j][i]);
      pk.u[j] = *(unsigned short*)&h;
    }
    *(short8*)&X2T[((size_t)b * 64 + i) * 4096 + n0 + r0] = pk.v;
  }
}

// ---------------------------------------------------------------------------
// S[b][m] = (t_emb @ dense_real + i t_emb @ dense_imag) * c_m / 4096
// ---------------------------------------------------------------------------
__global__ __launch_bounds__(256) void t_mod_kernel(const float* __restrict__ t_emb,
                                                    const float* __restrict__ dr,
                                                    const float* __restrict__ di,
                                                    float* __restrict__ Sr,
                                                    float* __restrict__ Si) {
  int b = blockIdx.x;
  __shared__ float te[256];
  te[threadIdx.x] = t_emb[b * 256 + threadIdx.x];
  __syncthreads();
  for (int m = threadIdx.x; m < 257; m += 256) {
    float ar = 0.f, ai = 0.f;
    for (int t = 0; t < 256; ++t) {
      float e = te[t];
      ar += e * dr[t * 257 + m];
      ai += e * di[t * 257 + m];
    }
    float c = (m == 0 ? 1.0f : 2.0f) * (1.0f / 4096.0f);
    Sr[b * 257 + m] = ar * c;
    Si[b * 257 + m] = ai * c;
  }
}

// ---------------------------------------------------------------------------
// Shared MFMA GEMM core (m97 structure, T2 pre-swizzled-source chunk swizzle)
// ---------------------------------------------------------------------------
__device__ __forceinline__ void gemm_core(const __hip_bfloat16* __restrict__ A, int lda, int m0,
                                          const __hip_bfloat16* __restrict__ B, int ldb, int n0,
                                          int k0, int ksteps,
                                          __hip_bfloat16* As, __hip_bfloat16* Bs,
                                          f32x4 acc[4][4]) {
  const int tid  = threadIdx.x;
  const int lane = tid & 63;
  const int wv   = tid >> 6;
  const int wr   = (wv >> 1) * 64;
  const int wc   = (wv & 1) * 64;
  const int fr   = lane & 15;
  const int fq   = lane >> 4;

  for (int ks = 0; ks < ksteps; ++ks) {
    int kt = k0 + ks * 64;
#pragma unroll
    for (int j = 0; j < 4; ++j) {
      int c   = j * 256 + tid;           // 0..1023
      int row = c >> 3;
      int chg = (c & 7) ^ (row & 7);     // swizzled source chunk
      const __hip_bfloat16* ga = A + (size_t)(m0 + row) * lda + kt + chg * 8;
      const __hip_bfloat16* gb = B + (size_t)(n0 + row) * ldb + kt + chg * 8;
      __hip_bfloat16* la = As + (size_t)(j * 256 + (tid & 192)) * 8;
      __hip_bfloat16* lb = Bs + (size_t)(j * 256 + (tid & 192)) * 8;
      __builtin_amdgcn_global_load_lds((as1_void*)ga, (as3_void*)la, 16, 0, 0);
      __builtin_amdgcn_global_load_lds((as1_void*)gb, (as3_void*)lb, 16, 0, 0);
    }
    __syncthreads();
#pragma unroll
    for (int kk = 0; kk < 2; ++kk) {
      short8 av[4], bv[4];
#pragma unroll
      for (int m = 0; m < 4; ++m) {
        int row  = wr + m * 16 + fr;
        int slot = (fq + kk * 4) ^ (row & 7);
        av[m] = *(const short8*)(As + row * 64 + slot * 8);
      }
#pragma unroll
      for (int n = 0; n < 4; ++n) {
        int row  = wc + n * 16 + fr;
        int slot = (fq + kk * 4) ^ (row & 7);
        bv[n] = *(const short8*)(Bs + row * 64 + slot * 8);
      }
#pragma unroll
      for (int m = 0; m < 4; ++m)
#pragma unroll
        for (int n = 0; n < 4; ++n)
          acc[m][n] = __builtin_amdgcn_mfma_f32_16x16x32_bf16(av[m], bv[n], acc[m][n], 0, 0, 0);
    }
    __syncthreads();
  }
}

// GEMM1: C1[z][mm][bi] (fp32 split-K partials) = F2 @ X2T^T
__global__ __launch_bounds__(256) void gemm1_kernel(const __hip_bfloat16* __restrict__ F2,
                                                    const __hip_bfloat16* __restrict__ X2T,
                                                    float* __restrict__ C1, int kchunk) {
  __shared__ __hip_bfloat16 As[128 * 64];
  __shared__ __hip_bfloat16 Bs[128 * 64];
  int n0 = blockIdx.x * 128;
  int m0 = blockIdx.y * 128;
  int k0 = blockIdx.z * kchunk;
  f32x4 acc[4][4];
#pragma unroll
  for (int m = 0; m < 4; ++m)
#pragma unroll
    for (int n = 0; n < 4; ++n)
#pragma unroll
      for (int r = 0; r < 4; ++r) acc[m][n][r] = 0.f;

  gemm_core(F2, 4096, m0, X2T, 4096, n0, k0, kchunk >> 6, As, Bs, acc);

  const int lane = threadIdx.x & 63;
  const int wv   = threadIdx.x >> 6;
  const int wr   = (wv >> 1) * 64, wc = (wv & 1) * 64;
  const int fr   = lane & 15, fq = lane >> 4;
  float* P = C1 + (size_t)blockIdx.z * (640 * 2048);
#pragma unroll
  for (int m = 0; m < 4; ++m)
#pragma unroll
    for (int n = 0; n < 4; ++n)
#pragma unroll
      for (int j = 0; j < 4; ++j) {
        int row = m0 + wr + m * 16 + fq * 4 + j;
        if (row >= 514) continue;                 // rows 514..639 are dead
        int col = n0 + wc + n * 16 + fr;
        P[(size_t)row * 2048 + col] = acc[m][n][j];
      }
}

// ---------------------------------------------------------------------------
// Mode mix (fused split-K reduce): per (k, quadrant q of 8 batches):
//   xsum = sum_z C1[z][k / 257+k][q*512 .. +512)       (into LDS)
//   Y[b][o] = ((x . W) * S)  -> Y2 bf16 rows k, 257+k
// ---------------------------------------------------------------------------
__global__ __launch_bounds__(256) void mix_kernel(const float* __restrict__ C1,
                                                  const float* __restrict__ Wr,
                                                  const float* __restrict__ Wi,
                                                  const float* __restrict__ Sr,
                                                  const float* __restrict__ Si,
                                                  __hip_bfloat16* __restrict__ Y2,
                                                  int splitk) {
  const int k = blockIdx.x;   // 0..256
  const int q = blockIdx.y;   // 0..3 (batches q*8 .. q*8+7)
  const int tid = threadIdx.x;
  __shared__ float wlr[4096];
  __shared__ float wli[4096];
  __shared__ float xs[1024];   // [0..511]=real, [512..1023]=imag; col = bl*64+i

  // stage weights for mode k (32 KB)
  const float* wrg = Wr + (size_t)k * 4096;
  const float* wig = Wi + (size_t)k * 4096;
  for (int c = tid; c < 1024; c += 256) {
    *(float4*)&wlr[c * 4] = *(const float4*)&wrg[c * 4];
    *(float4*)&wli[c * 4] = *(const float4*)&wig[c * 4];
  }
  // fused split-K reduce of this block's 512-column segment
  const size_t PST = 640ull * 2048;
  for (int idx = tid; idx < 1024; idx += 256) {
    int part = idx >> 9;
    int c    = idx & 511;
    const float* src = C1 + (size_t)(part ? 257 + k : k) * 2048 + q * 512 + c;
    float s = 0.f;
    for (int z = 0; z < splitk; ++z) s += src[(size_t)z * PST];
    xs[idx] = s;
  }
  __syncthreads();

  const int o  = tid & 63;
  const int jj = tid >> 6;          // 0..3
  const int bl0 = jj * 2, bl1 = jj * 2 + 1;
  float pr0 = 0.f, pi0 = 0.f, pr1 = 0.f, pi1 = 0.f;
#pragma unroll 8
  for (int i = 0; i < 64; ++i) {
    float wrv = wlr[i * 64 + o];
    float wiv = wli[i * 64 + o];
    float xr0 = xs[bl0 * 64 + i], xi0 = xs[512 + bl0 * 64 + i];
    float xr1 = xs[bl1 * 64 + i], xi1 = xs[512 + bl1 * 64 + i];
    pr0 += xr0 * wrv - xi0 * wiv;
    pi0 += xr0 * wiv + xi0 * wrv;
    pr1 += xr1 * wrv - xi1 * wiv;
    pi1 += xr1 * wiv + xi1 * wrv;
  }
  int b0 = q * 8 + bl0, b1 = q * 8 + bl1;
  float sr0 = Sr[b0 * 257 + k], si0 = Si[b0 * 257 + k];
  float sr1 = Sr[b1 * 257 + k], si1 = Si[b1 * 257 + k];
  Y2[(size_t)k * 2048 + b0 * 64 + o]         = __float2bfloat16(pr0 * sr0 - pi0 * si0);
  Y2[(size_t)(257 + k) * 2048 + b0 * 64 + o] = __float2bfloat16(pr0 * si0 + pi0 * sr0);
  Y2[(size_t)k * 2048 + b1 * 64 + o]         = __float2bfloat16(pr1 * sr1 - pi1 * si1);
  Y2[(size_t)(257 + k) * 2048 + b1 * 64 + o] = __float2bfloat16(pr1 * si1 + pi1 * sr1);
}

// Y2 [514][2048] -> Y2T [2048][576] (cols >= 514 zero-filled)
__global__ __launch_bounds__(256) void transpose_y_kernel(const __hip_bfloat16* __restrict__ Y2,
                                                          __hip_bfloat16* __restrict__ Y2T) {
  int kt = blockIdx.x;   // 0..8
  int bt = blockIdx.y;   // 0..31
  int k0 = kt * 64, b0 = bt * 64;
  __shared__ unsigned short tile[64][65];
  const unsigned short* src = (const unsigned short*)Y2;
#pragma unroll
  for (int it = 0; it < 16; ++it) {
    int c = it * 256 + threadIdx.x;
    int r = c >> 6, cc = c & 63;
    tile[r][cc] = (k0 + r < 514) ? src[(size_t)(k0 + r) * 2048 + b0 + cc] : (unsigned short)0;
  }
  __syncthreads();
  unsigned short* dst = (unsigned short*)Y2T;
#pragma unroll
  for (int it = 0; it < 16; ++it) {
    int c = it * 256 + threadIdx.x;
    int orow = c >> 6, ocol = c & 63;    // orow = bo, ocol = kk
    dst[(size_t)(b0 + orow) * 576 + k0 + ocol] = tile[ocol][orow];
  }
}

// GEMM2: out[b][n][o] = Gm[n][:] . Y2T[bo][:]
__global__ __launch_bounds__(256) void gemm2_kernel(const __hip_bfloat16* __restrict__ Gm,
                                                    const __hip_bfloat16* __restrict__ Y2T,
                                                    float* __restrict__ out) {
  __shared__ __hip_bfloat16 As[128 * 64];
  __shared__ __hip_bfloat16 Bs[128 * 64];
  int n0 = blockIdx.x * 128;   // bo
  int m0 = blockIdx.y * 128;   // n (time)
  f32x4 acc[4][4];
#pragma unroll
  for (int m = 0; m < 4; ++m)
#pragma unroll
    for (int n = 0; n < 4; ++n)
#pragma unroll
      for (int r = 0; r < 4; ++r) acc[m][n][r] = 0.f;

  gemm_core(Gm, 576, m0, Y2T, 576, n0, 0, 9, As, Bs, acc);

  const int lane = threadIdx.x & 63;
  const int wv   = threadIdx.x >> 6;
  const int wr   = (wv >> 1) * 64, wc = (wv & 1) * 64;
  const int fr   = lane & 15, fq = lane >> 4;
#pragma unroll
  for (int m = 0; m < 4; ++m)
#pragma unroll
    for (int n = 0; n < 4; ++n)
#pragma unroll
      for (int j = 0; j < 4; ++j) {
        int row = m0 + wr + m * 16 + fq * 4 + j;   // n index
        int col = n0 + wc + n * 16 + fr;           // bo index
        int b = col >> 6, o = col & 63;
        out[((size_t)b * 4096 + row) * 64 + o] = acc[m][n][j];
      }
}

// ---------------------------------------------------------------------------
extern "C" void kernel_launch(void* const* d_in, const int* in_sizes, int n_in,
                              void* d_out, int out_size, void* d_ws, size_t ws_size,
                              hipStream_t stream) {
  const float* x  = (const float*)d_in[0];   // (32,4096,64)
  const float* te = (const float*)d_in[1];   // (32,256)
  const float* wr = (const float*)d_in[2];   // (257,64,64)
  const float* wi = (const float*)d_in[3];
  const float* dr = (const float*)d_in[4];   // (256,257)
  const float* di = (const float*)d_in[5];
  float* out = (float*)d_out;

  char* p = (char*)d_ws;
  auto alloc = [&](size_t bytes) -> char* {
    char* r = p;
    p += (bytes + 255) & ~(size_t)255;
    return r;
  };
  __hip_bfloat16* F2  = (__hip_bfloat16*)alloc(640ull * 4096 * 2);
  __hip_bfloat16* Gm  = (__hip_bfloat16*)alloc(4096ull * 576 * 2);
  __hip_bfloat16* X2T = (__hip_bfloat16*)alloc(2048ull * 4096 * 2);
  float* Sr = (float*)alloc(32 * 257 * 4);
  float* Si = (float*)alloc(32 * 257 * 4);
  __hip_bfloat16* Y2  = (__hip_bfloat16*)alloc(514ull * 2048 * 2);
  __hip_bfloat16* Y2T = (__hip_bfloat16*)alloc(2048ull * 576 * 2);
  size_t fixed = (size_t)(p - (char*)d_ws);

  int splitk = 1;
  if (ws_size >= fixed + 8ull * 640 * 2048 * 4)      splitk = 8;
  else if (ws_size >= fixed + 4ull * 640 * 2048 * 4) splitk = 4;
  else if (ws_size >= fixed + 2ull * 640 * 2048 * 4) splitk = 2;
  float* C1 = (float*)alloc((size_t)splitk * 640 * 2048 * 4);
  int kchunk = 4096 / splitk;

  gen_f2_kernel<<<10240, 256, 0, stream>>>(F2);
  gen_gm_kernel<<<4096, 256, 0, stream>>>(Gm);
  transpose_x_kernel<<<dim3(64, 32), 256, 0, stream>>>(x, X2T);
  t_mod_kernel<<<32, 256, 0, stream>>>(te, dr, di, Sr, Si);
  gemm1_kernel<<<dim3(16, 5, splitk), 256, 0, stream>>>(F2, X2T, C1, kchunk);
  mix_kernel<<<dim3(257, 4), 256, 0, stream>>>(C1, wr, wi, Sr, Si, Y2, splitk);
  transpose_y_kernel<<<dim3(9, 32), 256, 0, stream>>>(Y2, Y2T);
  gemm2_kernel<<<dim3(16, 32), 256, 0, stream>>>(Gm, Y2T, out);
}

// Round 3
// 111.620 us; speedup vs baseline: 1.2047x; 1.1321x over previous
//
#include <hip/hip_runtime.h>
#include <hip/hip_bf16.h>

typedef short short8 __attribute__((ext_vector_type(8)));
typedef float f32x4 __attribute__((ext_vector_type(4)));
typedef const void __attribute__((address_space(1))) as1_void;
typedef void __attribute__((address_space(3))) as3_void;

// hardware trig: input in revolutions (D = sin/cos(S0 * 2pi)), already in [0,1)
__device__ __forceinline__ float sin_rev(float r) {
  float o; asm("v_sin_f32 %0, %1" : "=v"(o) : "v"(r)); return o;
}
__device__ __forceinline__ float cos_rev(float r) {
  float o; asm("v_cos_f32 %0, %1" : "=v"(o) : "v"(r)); return o;
}

#define INV4096 0.000244140625f

// ---------------------------------------------------------------------------
// prep_kernel: range-partitioned roles (block-uniform branch):
//   [0, 10240)          F2 [640][4096] bf16: rows 0..256 cos, 257..513 -sin, rest 0
//   [10240, 14336)      Gm [4096][576] bf16: cols 0..256 cos, 257..513 -sin, rest 0
//   [14336, 14368)      S[b][m] = (t_emb@dense_r + i t_emb@dense_i) * c_m/4096
//   [14368, 14944)      zero-fill Y2T [2048][576] (mix later overwrites cols 0..513)
// ---------------------------------------------------------------------------
__global__ __launch_bounds__(256) void prep_kernel(__hip_bfloat16* __restrict__ F2,
                                                   __hip_bfloat16* __restrict__ Gm,
                                                   const float* __restrict__ t_emb,
                                                   const float* __restrict__ dr,
                                                   const float* __restrict__ di,
                                                   float* __restrict__ Sr,
                                                   float* __restrict__ Si,
                                                   __hip_bfloat16* __restrict__ Y2T) {
  const int bid = blockIdx.x;
  const int tid = threadIdx.x;
  __shared__ float te[256];

  if (bid < 10240) {
    unsigned gid = bid * 256u + tid;   // < 640*4096
    int mm = gid >> 12;
    int n  = gid & 4095;
    float v = 0.f;
    if (mm < 257)      v =  cos_rev((float)((mm * n) & 4095) * INV4096);
    else if (mm < 514) v = -sin_rev((float)(((mm - 257) * n) & 4095) * INV4096);
    F2[gid] = __float2bfloat16(v);
  } else if (bid < 14336) {
    int n = bid - 10240;   // 0..4095
    for (int kk = tid; kk < 576; kk += 256) {
      float v = 0.f;
      if (kk < 257)      v =  cos_rev((float)((kk * n) & 4095) * INV4096);
      else if (kk < 514) v = -sin_rev((float)(((kk - 257) * n) & 4095) * INV4096);
      Gm[(size_t)n * 576 + kk] = __float2bfloat16(v);
    }
  } else if (bid < 14368) {
    int b = bid - 14336;   // 0..31
    te[tid] = t_emb[b * 256 + tid];
    __syncthreads();
    for (int m = tid; m < 257; m += 256) {
      float ar = 0.f, ai = 0.f;
      for (int t = 0; t < 256; ++t) {
        float e = te[t];
        ar += e * dr[t * 257 + m];
        ai += e * di[t * 257 + m];
      }
      float c = (m == 0 ? 1.0f : 2.0f) * (1.0f / 4096.0f);
      Sr[b * 257 + m] = ar * c;
      Si[b * 257 + m] = ai * c;
    }
  } else {
    int zb = bid - 14368;  // 0..575 ; 576*256 chunks of 8 shorts = 2048*576
    short8 z;
#pragma unroll
    for (int i = 0; i < 8; ++i) z[i] = 0;
    *(short8*)&((unsigned short*)Y2T)[((size_t)zb * 256 + tid) * 8] = z;
  }
}

// ---------------------------------------------------------------------------
// x (f32 [32][4096][64]) -> X2T (bf16 [2048][4096]),  X2T[b*64+i][n] = x[b][n][i]
// ---------------------------------------------------------------------------
__global__ __launch_bounds__(256) void transpose_x_kernel(const float* __restrict__ x,
                                                          __hip_bfloat16* __restrict__ X2T) {
  int nt = blockIdx.x;   // 0..63
  int b  = blockIdx.y;   // 0..31
  int n0 = nt * 64;
  __shared__ float tile[64][65];
#pragma unroll
  for (int it = 0; it < 4; ++it) {
    int c = it * 256 + threadIdx.x;       // 0..1023 float4 chunks
    int r = c >> 4, i4 = (c & 15) * 4;
    float4 v = *(const float4*)&x[((size_t)b * 4096 + n0 + r) * 64 + i4];
    tile[r][i4 + 0] = v.x; tile[r][i4 + 1] = v.y;
    tile[r][i4 + 2] = v.z; tile[r][i4 + 3] = v.w;
  }
  __syncthreads();
#pragma unroll
  for (int it = 0; it < 2; ++it) {
    int c = it * 256 + threadIdx.x;       // 0..511
    int i = c & 63, r0 = (c >> 6) * 8;
    union { short8 v; unsigned short u[8]; } pk;
#pragma unroll
    for (int j = 0; j < 8; ++j) {
      __hip_bfloat16 h = __float2bfloat16(tile[r0 + j][i]);
      pk.u[j] = *(unsigned short*)&h;
    }
    *(short8*)&X2T[((size_t)b * 64 + i) * 4096 + n0 + r0] = pk.v;
  }
}

// ---------------------------------------------------------------------------
// Shared MFMA GEMM core (m97 structure, T2 pre-swizzled-source chunk swizzle)
// ---------------------------------------------------------------------------
__device__ __forceinline__ void gemm_core(const __hip_bfloat16* __restrict__ A, int lda, int m0,
                                          const __hip_bfloat16* __restrict__ B, int ldb, int n0,
                                          int k0, int ksteps,
                                          __hip_bfloat16* As, __hip_bfloat16* Bs,
                                          f32x4 acc[4][4]) {
  const int tid  = threadIdx.x;
  const int lane = tid & 63;
  const int wv   = tid >> 6;
  const int wr   = (wv >> 1) * 64;
  const int wc   = (wv & 1) * 64;
  const int fr   = lane & 15;
  const int fq   = lane >> 4;

  for (int ks = 0; ks < ksteps; ++ks) {
    int kt = k0 + ks * 64;
#pragma unroll
    for (int j = 0; j < 4; ++j) {
      int c   = j * 256 + tid;           // 0..1023
      int row = c >> 3;
      int chg = (c & 7) ^ (row & 7);     // swizzled source chunk
      const __hip_bfloat16* ga = A + (size_t)(m0 + row) * lda + kt + chg * 8;
      const __hip_bfloat16* gb = B + (size_t)(n0 + row) * ldb + kt + chg * 8;
      __hip_bfloat16* la = As + (size_t)(j * 256 + (tid & 192)) * 8;
      __hip_bfloat16* lb = Bs + (size_t)(j * 256 + (tid & 192)) * 8;
      __builtin_amdgcn_global_load_lds((as1_void*)ga, (as3_void*)la, 16, 0, 0);
      __builtin_amdgcn_global_load_lds((as1_void*)gb, (as3_void*)lb, 16, 0, 0);
    }
    __syncthreads();
#pragma unroll
    for (int kk = 0; kk < 2; ++kk) {
      short8 av[4], bv[4];
#pragma unroll
      for (int m = 0; m < 4; ++m) {
        int row  = wr + m * 16 + fr;
        int slot = (fq + kk * 4) ^ (row & 7);
        av[m] = *(const short8*)(As + row * 64 + slot * 8);
      }
#pragma unroll
      for (int n = 0; n < 4; ++n) {
        int row  = wc + n * 16 + fr;
        int slot = (fq + kk * 4) ^ (row & 7);
        bv[n] = *(const short8*)(Bs + row * 64 + slot * 8);
      }
#pragma unroll
      for (int m = 0; m < 4; ++m)
#pragma unroll
        for (int n = 0; n < 4; ++n)
          acc[m][n] = __builtin_amdgcn_mfma_f32_16x16x32_bf16(av[m], bv[n], acc[m][n], 0, 0, 0);
    }
    __syncthreads();
  }
}

// GEMM1: C1[z][mm][bi] (bf16 split-K partials) = F2 @ X2T^T
__global__ __launch_bounds__(256) void gemm1_kernel(const __hip_bfloat16* __restrict__ F2,
                                                    const __hip_bfloat16* __restrict__ X2T,
                                                    __hip_bfloat16* __restrict__ C1, int kchunk) {
  __shared__ __hip_bfloat16 As[128 * 64];
  __shared__ __hip_bfloat16 Bs[128 * 64];
  int n0 = blockIdx.x * 128;
  int m0 = blockIdx.y * 128;
  int k0 = blockIdx.z * kchunk;
  f32x4 acc[4][4];
#pragma unroll
  for (int m = 0; m < 4; ++m)
#pragma unroll
    for (int n = 0; n < 4; ++n)
#pragma unroll
      for (int r = 0; r < 4; ++r) acc[m][n][r] = 0.f;

  gemm_core(F2, 4096, m0, X2T, 4096, n0, k0, kchunk >> 6, As, Bs, acc);

  const int lane = threadIdx.x & 63;
  const int wv   = threadIdx.x >> 6;
  const int wr   = (wv >> 1) * 64, wc = (wv & 1) * 64;
  const int fr   = lane & 15, fq = lane >> 4;
  __hip_bfloat16* P = C1 + (size_t)blockIdx.z * (640 * 2048);
#pragma unroll
  for (int m = 0; m < 4; ++m)
#pragma unroll
    for (int n = 0; n < 4; ++n)
#pragma unroll
      for (int j = 0; j < 4; ++j) {
        int row = m0 + wr + m * 16 + fq * 4 + j;
        if (row >= 514) continue;                 // rows 514..639 are dead
        int col = n0 + wc + n * 16 + fr;
        P[(size_t)row * 2048 + col] = __float2bfloat16(acc[m][n][j]);
      }
}

// ---------------------------------------------------------------------------
// Mode mix (fused split-K reduce, direct transposed output):
// per (k, quadrant q): xsum = sum_z C1[z][k / 257+k][q*512..+512)   (LDS)
//   Y[b][o] = ((x . W) * S)  ->  Y2T[b*64+o][k], Y2T[b*64+o][257+k]
// ---------------------------------------------------------------------------
__global__ __launch_bounds__(256) void mix_kernel(const __hip_bfloat16* __restrict__ C1,
                                                  const float* __restrict__ Wr,
                                                  const float* __restrict__ Wi,
                                                  const float* __restrict__ Sr,
                                                  const float* __restrict__ Si,
                                                  __hip_bfloat16* __restrict__ Y2T,
                                                  int splitk) {
  const int k = blockIdx.x;   // 0..256
  const int q = blockIdx.y;   // 0..3 (batches q*8 .. q*8+7)
  const int tid = threadIdx.x;
  __shared__ float wlr[4096];
  __shared__ float wli[4096];
  __shared__ float xs[1024];   // [0..511]=real, [512..1023]=imag; col = bl*64+i

  // stage weights for mode k (32 KB)
  const float* wrg = Wr + (size_t)k * 4096;
  const float* wig = Wi + (size_t)k * 4096;
  for (int c = tid; c < 1024; c += 256) {
    *(float4*)&wlr[c * 4] = *(const float4*)&wrg[c * 4];
    *(float4*)&wli[c * 4] = *(const float4*)&wig[c * 4];
  }
  // fused split-K reduce of this block's 512-column segment
  const size_t PST = 640ull * 2048;
  for (int idx = tid; idx < 1024; idx += 256) {
    int part = idx >> 9;
    int c    = idx & 511;
    const __hip_bfloat16* src = C1 + (size_t)(part ? 257 + k : k) * 2048 + q * 512 + c;
    float s = 0.f;
    for (int z = 0; z < splitk; ++z) s += __bfloat162float(src[(size_t)z * PST]);
    xs[idx] = s;
  }
  __syncthreads();

  const int o  = tid & 63;
  const int jj = tid >> 6;          // 0..3
  const int bl0 = jj * 2, bl1 = jj * 2 + 1;
  float pr0 = 0.f, pi0 = 0.f, pr1 = 0.f, pi1 = 0.f;
#pragma unroll 8
  for (int i = 0; i < 64; ++i) {
    float wrv = wlr[i * 64 + o];
    float wiv = wli[i * 64 + o];
    float xr0 = xs[bl0 * 64 + i], xi0 = xs[512 + bl0 * 64 + i];
    float xr1 = xs[bl1 * 64 + i], xi1 = xs[512 + bl1 * 64 + i];
    pr0 += xr0 * wrv - xi0 * wiv;
    pi0 += xr0 * wiv + xi0 * wrv;
    pr1 += xr1 * wrv - xi1 * wiv;
    pi1 += xr1 * wiv + xi1 * wrv;
  }
  int b0 = q * 8 + bl0, b1 = q * 8 + bl1;
  float sr0 = Sr[b0 * 257 + k], si0 = Si[b0 * 257 + k];
  float sr1 = Sr[b1 * 257 + k], si1 = Si[b1 * 257 + k];
  size_t r0 = (size_t)(b0 * 64 + o) * 576;
  size_t r1 = (size_t)(b1 * 64 + o) * 576;
  Y2T[r0 + k]       = __float2bfloat16(pr0 * sr0 - pi0 * si0);
  Y2T[r0 + 257 + k] = __float2bfloat16(pr0 * si0 + pi0 * sr0);
  Y2T[r1 + k]       = __float2bfloat16(pr1 * sr1 - pi1 * si1);
  Y2T[r1 + 257 + k] = __float2bfloat16(pr1 * si1 + pi1 * sr1);
}

// GEMM2: out[b][n][o] = Gm[n][:] . Y2T[bo][:]
__global__ __launch_bounds__(256) void gemm2_kernel(const __hip_bfloat16* __restrict__ Gm,
                                                    const __hip_bfloat16* __restrict__ Y2T,
                                                    float* __restrict__ out) {
  __shared__ __hip_bfloat16 As[128 * 64];
  __shared__ __hip_bfloat16 Bs[128 * 64];
  int n0 = blockIdx.x * 128;   // bo
  int m0 = blockIdx.y * 128;   // n (time)
  f32x4 acc[4][4];
#pragma unroll
  for (int m = 0; m < 4; ++m)
#pragma unroll
    for (int n = 0; n < 4; ++n)
#pragma unroll
      for (int r = 0; r < 4; ++r) acc[m][n][r] = 0.f;

  gemm_core(Gm, 576, m0, Y2T, 576, n0, 0, 9, As, Bs, acc);

  const int lane = threadIdx.x & 63;
  const int wv   = threadIdx.x >> 6;
  const int wr   = (wv >> 1) * 64, wc = (wv & 1) * 64;
  const int fr   = lane & 15, fq = lane >> 4;
#pragma unroll
  for (int m = 0; m < 4; ++m)
#pragma unroll
    for (int n = 0; n < 4; ++n)
#pragma unroll
      for (int j = 0; j < 4; ++j) {
        int row = m0 + wr + m * 16 + fq * 4 + j;   // n index
        int col = n0 + wc + n * 16 + fr;           // bo index
        int b = col >> 6, o = col & 63;
        out[((size_t)b * 4096 + row) * 64 + o] = acc[m][n][j];
      }
}

// ---------------------------------------------------------------------------
extern "C" void kernel_launch(void* const* d_in, const int* in_sizes, int n_in,
                              void* d_out, int out_size, void* d_ws, size_t ws_size,
                              hipStream_t stream) {
  const float* x  = (const float*)d_in[0];   // (32,4096,64)
  const float* te = (const float*)d_in[1];   // (32,256)
  const float* wr = (const float*)d_in[2];   // (257,64,64)
  const float* wi = (const float*)d_in[3];
  const float* dr = (const float*)d_in[4];   // (256,257)
  const float* di = (const float*)d_in[5];
  float* out = (float*)d_out;

  char* p = (char*)d_ws;
  auto alloc = [&](size_t bytes) -> char* {
    char* r = p;
    p += (bytes + 255) & ~(size_t)255;
    return r;
  };
  __hip_bfloat16* F2  = (__hip_bfloat16*)alloc(640ull * 4096 * 2);
  __hip_bfloat16* Gm  = (__hip_bfloat16*)alloc(4096ull * 576 * 2);
  __hip_bfloat16* X2T = (__hip_bfloat16*)alloc(2048ull * 4096 * 2);
  float* Sr = (float*)alloc(32 * 257 * 4);
  float* Si = (float*)alloc(32 * 257 * 4);
  __hip_bfloat16* Y2T = (__hip_bfloat16*)alloc(2048ull * 576 * 2);
  size_t fixed = (size_t)(p - (char*)d_ws);

  int splitk = 1;
  if (ws_size >= fixed + 8ull * 640 * 2048 * 2)      splitk = 8;
  else if (ws_size >= fixed + 4ull * 640 * 2048 * 2) splitk = 4;
  else if (ws_size >= fixed + 2ull * 640 * 2048 * 2) splitk = 2;
  __hip_bfloat16* C1 = (__hip_bfloat16*)alloc((size_t)splitk * 640 * 2048 * 2);
  int kchunk = 4096 / splitk;

  prep_kernel<<<14944, 256, 0, stream>>>(F2, Gm, te, dr, di, Sr, Si, Y2T);
  transpose_x_kernel<<<dim3(64, 32), 256, 0, stream>>>(x, X2T);
  gemm1_kernel<<<dim3(16, 5, splitk), 256, 0, stream>>>(F2, X2T, C1, kchunk);
  mix_kernel<<<dim3(257, 4), 256, 0, stream>>>(C1, wr, wi, Sr, Si, Y2T, splitk);
  gemm2_kernel<<<dim3(16, 32), 256, 0, stream>>>(Gm, Y2T, out);
}

// Round 4
// 110.928 us; speedup vs baseline: 1.2122x; 1.0062x over previous
//
#include <hip/hip_runtime.h>
#include <hip/hip_bf16.h>

typedef short short8 __attribute__((ext_vector_type(8)));
typedef float f32x4 __attribute__((ext_vector_type(4)));
typedef const void __attribute__((address_space(1))) as1_void;
typedef void __attribute__((address_space(3))) as3_void;

// hardware trig: input in revolutions (D = sin/cos(S0 * 2pi)), already in [0,1)
__device__ __forceinline__ float sin_rev(float r) {
  float o; asm("v_sin_f32 %0, %1" : "=v"(o) : "v"(r)); return o;
}
__device__ __forceinline__ float cos_rev(float r) {
  float o; asm("v_cos_f32 %0, %1" : "=v"(o) : "v"(r)); return o;
}

#define INV4096 0.000244140625f
#define INV16   0.0625f

// ---------------------------------------------------------------------------
// prep_kernel: range-partitioned roles (block-uniform branch):
//   [0, 8192)       F2 [512][4096] bf16: rows 0..255 = cos m, 256..511 = -sin (m=row-255)
//   [8192, 12288)   Gm [4096][512] bf16: cols 0..255 = cos k, 256..511 = -sin (k=col-255)
//   [12288, 12320)  S[b][m] = (t_emb@dense_r + i t_emb@dense_i) * c_m/4096
//   [12320, 14368)  transpose: x (f32 [32][4096][64]) -> X2T bf16 [2048][4096]
//                   + sigma[s][bi] += sum_{n=s mod 16} x[n][bi]  (fp32 atomics)
// ---------------------------------------------------------------------------
__global__ __launch_bounds__(256) void prep_kernel(__hip_bfloat16* __restrict__ F2,
                                                   __hip_bfloat16* __restrict__ Gm,
                                                   const float* __restrict__ t_emb,
                                                   const float* __restrict__ dr,
                                                   const float* __restrict__ di,
                                                   float* __restrict__ Sr,
                                                   float* __restrict__ Si,
                                                   const float* __restrict__ x,
                                                   __hip_bfloat16* __restrict__ X2T,
                                                   float* __restrict__ sigma) {
  const int bid = blockIdx.x;
  const int tid = threadIdx.x;
  __shared__ float te[256];
  __shared__ float tile[64][65];

  if (bid < 8192) {
    unsigned gid = bid * 256u + tid;   // < 512*4096
    int row = gid >> 12;
    int n   = gid & 4095;
    float v;
    if (row < 256) v =  cos_rev((float)((row * n) & 4095) * INV4096);
    else           v = -sin_rev((float)(((row - 255) * n) & 4095) * INV4096);
    F2[gid] = __float2bfloat16(v);
  } else if (bid < 12288) {
    int n = bid - 8192;   // 0..4095
#pragma unroll
    for (int it = 0; it < 2; ++it) {
      int kk = it * 256 + tid;   // 0..511
      float v;
      if (kk < 256) v =  cos_rev((float)((kk * n) & 4095) * INV4096);
      else          v = -sin_rev((float)(((kk - 255) * n) & 4095) * INV4096);
      Gm[(size_t)n * 512 + kk] = __float2bfloat16(v);
    }
  } else if (bid < 12320) {
    int b = bid - 12288;   // 0..31
    te[tid] = t_emb[b * 256 + tid];
    __syncthreads();
    for (int m = tid; m < 257; m += 256) {
      float ar = 0.f, ai = 0.f;
      for (int t = 0; t < 256; ++t) {
        float e = te[t];
        ar += e * dr[t * 257 + m];
        ai += e * di[t * 257 + m];
      }
      float c = (m == 0 ? 1.0f : 2.0f) * (1.0f / 4096.0f);
      Sr[b * 257 + m] = ar * c;
      Si[b * 257 + m] = ai * c;
    }
  } else {
    int idx = bid - 12320;        // 0..2047
    int nt = idx & 63;            // n-tile
    int b  = idx >> 6;            // batch
    int n0 = nt * 64;
#pragma unroll
    for (int it = 0; it < 4; ++it) {
      int c = it * 256 + tid;     // 0..1023 float4 chunks
      int r = c >> 4, i4 = (c & 15) * 4;
      float4 v = *(const float4*)&x[((size_t)b * 4096 + n0 + r) * 64 + i4];
      tile[r][i4 + 0] = v.x; tile[r][i4 + 1] = v.y;
      tile[r][i4 + 2] = v.z; tile[r][i4 + 3] = v.w;
    }
    __syncthreads();
#pragma unroll
    for (int it = 0; it < 2; ++it) {
      int c = it * 256 + tid;     // 0..511
      int i = c & 63, r0 = (c >> 6) * 8;
      union { short8 v; unsigned short u[8]; } pk;
#pragma unroll
      for (int j = 0; j < 8; ++j) {
        __hip_bfloat16 h = __float2bfloat16(tile[r0 + j][i]);
        pk.u[j] = *(unsigned short*)&h;
      }
      *(short8*)&X2T[((size_t)b * 64 + i) * 4096 + n0 + r0] = pk.v;
    }
    // sigma partials: s = r mod 16 (n0 is a multiple of 16)
    int i = tid & 63, g = tid >> 6;   // g in 0..3 -> s = g*4..g*4+3
#pragma unroll
    for (int ds = 0; ds < 4; ++ds) {
      int s = g * 4 + ds;
      float v = tile[s][i] + tile[s + 16][i] + tile[s + 32][i] + tile[s + 48][i];
      atomicAdd(&sigma[(size_t)s * 2048 + b * 64 + i], v);
    }
  }
}

// ---------------------------------------------------------------------------
// Shared MFMA GEMM core (m97 structure, T2 pre-swizzled-source chunk swizzle)
// ---------------------------------------------------------------------------
__device__ __forceinline__ void gemm_core(const __hip_bfloat16* __restrict__ A, int lda, int m0,
                                          const __hip_bfloat16* __restrict__ B, int ldb, int n0,
                                          int k0, int ksteps,
                                          __hip_bfloat16* As, __hip_bfloat16* Bs,
                                          f32x4 acc[4][4]) {
  const int tid  = threadIdx.x;
  const int lane = tid & 63;
  const int wv   = tid >> 6;
  const int wr   = (wv >> 1) * 64;
  const int wc   = (wv & 1) * 64;
  const int fr   = lane & 15;
  const int fq   = lane >> 4;

  for (int ks = 0; ks < ksteps; ++ks) {
    int kt = k0 + ks * 64;
#pragma unroll
    for (int j = 0; j < 4; ++j) {
      int c   = j * 256 + tid;           // 0..1023
      int row = c >> 3;
      int chg = (c & 7) ^ (row & 7);     // swizzled source chunk
      const __hip_bfloat16* ga = A + (size_t)(m0 + row) * lda + kt + chg * 8;
      const __hip_bfloat16* gb = B + (size_t)(n0 + row) * ldb + kt + chg * 8;
      __hip_bfloat16* la = As + (size_t)(j * 256 + (tid & 192)) * 8;
      __hip_bfloat16* lb = Bs + (size_t)(j * 256 + (tid & 192)) * 8;
      __builtin_amdgcn_global_load_lds((as1_void*)ga, (as3_void*)la, 16, 0, 0);
      __builtin_amdgcn_global_load_lds((as1_void*)gb, (as3_void*)lb, 16, 0, 0);
    }
    __syncthreads();
#pragma unroll
    for (int kk = 0; kk < 2; ++kk) {
      short8 av[4], bv[4];
#pragma unroll
      for (int m = 0; m < 4; ++m) {
        int row  = wr + m * 16 + fr;
        int slot = (fq + kk * 4) ^ (row & 7);
        av[m] = *(const short8*)(As + row * 64 + slot * 8);
      }
#pragma unroll
      for (int n = 0; n < 4; ++n) {
        int row  = wc + n * 16 + fr;
        int slot = (fq + kk * 4) ^ (row & 7);
        bv[n] = *(const short8*)(Bs + row * 64 + slot * 8);
      }
#pragma unroll
      for (int m = 0; m < 4; ++m)
#pragma unroll
        for (int n = 0; n < 4; ++n)
          acc[m][n] = __builtin_amdgcn_mfma_f32_16x16x32_bf16(av[m], bv[n], acc[m][n], 0, 0, 0);
    }
    __syncthreads();
  }
}

// GEMM1: C1[z][row][bi] (bf16 split-K partials) = F2 @ X2T^T   (512 rows, all live)
__global__ __launch_bounds__(256) void gemm1_kernel(const __hip_bfloat16* __restrict__ F2,
                                                    const __hip_bfloat16* __restrict__ X2T,
                                                    __hip_bfloat16* __restrict__ C1, int kchunk) {
  __shared__ __hip_bfloat16 As[128 * 64];
  __shared__ __hip_bfloat16 Bs[128 * 64];
  int n0 = blockIdx.x * 128;
  int m0 = blockIdx.y * 128;
  int k0 = blockIdx.z * kchunk;
  f32x4 acc[4][4];
#pragma unroll
  for (int m = 0; m < 4; ++m)
#pragma unroll
    for (int n = 0; n < 4; ++n)
#pragma unroll
      for (int r = 0; r < 4; ++r) acc[m][n][r] = 0.f;

  gemm_core(F2, 4096, m0, X2T, 4096, n0, k0, kchunk >> 6, As, Bs, acc);

  const int lane = threadIdx.x & 63;
  const int wv   = threadIdx.x >> 6;
  const int wr   = (wv >> 1) * 64, wc = (wv & 1) * 64;
  const int fr   = lane & 15, fq = lane >> 4;
  __hip_bfloat16* P = C1 + (size_t)blockIdx.z * (512 * 2048);
#pragma unroll
  for (int m = 0; m < 4; ++m)
#pragma unroll
    for (int n = 0; n < 4; ++n)
#pragma unroll
      for (int j = 0; j < 4; ++j) {
        int row = m0 + wr + m * 16 + fq * 4 + j;
        int col = n0 + wc + n * 16 + fr;
        P[(size_t)row * 2048 + col] = __float2bfloat16(acc[m][n][j]);
      }
}

// ---------------------------------------------------------------------------
// Mode mix (fused split-K reduce, direct transposed output):
// per (k, quadrant q): xr = sum_z C1[z][k] (k<256) or sigma-combine (k=256)
//                      xi = sum_z C1[z][255+k] (k>=1) or 0 (k=0)
//   Y[b][o] = ((x . W) * S)  ->  Y2T[bo][k] (k<256) / Yx[bo] (k=256);
//                                Y2T[bo][255+k] (k>=1)
// ---------------------------------------------------------------------------
__global__ __launch_bounds__(256) void mix_kernel(const __hip_bfloat16* __restrict__ C1,
                                                  const float* __restrict__ sigma,
                                                  const float* __restrict__ Wr,
                                                  const float* __restrict__ Wi,
                                                  const float* __restrict__ Sr,
                                                  const float* __restrict__ Si,
                                                  __hip_bfloat16* __restrict__ Y2T,
                                                  __hip_bfloat16* __restrict__ Yx,
                                                  int splitk) {
  const int k = blockIdx.x;   // 0..256
  const int q = blockIdx.y;   // 0..3 (batches q*8 .. q*8+7)
  const int tid = threadIdx.x;
  __shared__ float wlr[4096];
  __shared__ float wli[4096];
  __shared__ float xs[1024];   // [0..511]=real, [512..1023]=imag; col = bl*64+i

  // stage weights for mode k (32 KB)
  const float* wrg = Wr + (size_t)k * 4096;
  const float* wig = Wi + (size_t)k * 4096;
  for (int c = tid; c < 1024; c += 256) {
    *(float4*)&wlr[c * 4] = *(const float4*)&wrg[c * 4];
    *(float4*)&wli[c * 4] = *(const float4*)&wig[c * 4];
  }
  // fused split-K reduce of this block's 512-column segment
  const size_t PST = 512ull * 2048;
  for (int idx = tid; idx < 1024; idx += 256) {
    int part = idx >> 9;
    int c    = idx & 511;
    float s = 0.f;
    if (part == 0) {
      if (k < 256) {
        const __hip_bfloat16* src = C1 + (size_t)k * 2048 + q * 512 + c;
        for (int z = 0; z < splitk; ++z) s += __bfloat162float(src[(size_t)z * PST]);
      } else {
        const float* sg = sigma + q * 512 + c;
#pragma unroll
        for (int ss = 0; ss < 16; ++ss)
          s += cos_rev((float)ss * INV16) * sg[(size_t)ss * 2048];
      }
    } else if (k > 0) {
      const __hip_bfloat16* src = C1 + (size_t)(255 + k) * 2048 + q * 512 + c;
      for (int z = 0; z < splitk; ++z) s += __bfloat162float(src[(size_t)z * PST]);
    }
    xs[idx] = s;
  }
  __syncthreads();

  const int o  = tid & 63;
  const int jj = tid >> 6;          // 0..3
  const int bl0 = jj * 2, bl1 = jj * 2 + 1;
  float pr0 = 0.f, pi0 = 0.f, pr1 = 0.f, pi1 = 0.f;
#pragma unroll 8
  for (int i = 0; i < 64; ++i) {
    float wrv = wlr[i * 64 + o];
    float wiv = wli[i * 64 + o];
    float xr0 = xs[bl0 * 64 + i], xi0 = xs[512 + bl0 * 64 + i];
    float xr1 = xs[bl1 * 64 + i], xi1 = xs[512 + bl1 * 64 + i];
    pr0 += xr0 * wrv - xi0 * wiv;
    pi0 += xr0 * wiv + xi0 * wrv;
    pr1 += xr1 * wrv - xi1 * wiv;
    pi1 += xr1 * wiv + xi1 * wrv;
  }
  int b0 = q * 8 + bl0, b1 = q * 8 + bl1;
  float sr0 = Sr[b0 * 257 + k], si0 = Si[b0 * 257 + k];
  float sr1 = Sr[b1 * 257 + k], si1 = Si[b1 * 257 + k];
  int bo0 = b0 * 64 + o, bo1 = b1 * 64 + o;
  __hip_bfloat16 yr0 = __float2bfloat16(pr0 * sr0 - pi0 * si0);
  __hip_bfloat16 yi0 = __float2bfloat16(pr0 * si0 + pi0 * sr0);
  __hip_bfloat16 yr1 = __float2bfloat16(pr1 * sr1 - pi1 * si1);
  __hip_bfloat16 yi1 = __float2bfloat16(pr1 * si1 + pi1 * sr1);
  if (k < 256) {
    Y2T[(size_t)bo0 * 512 + k] = yr0;
    Y2T[(size_t)bo1 * 512 + k] = yr1;
  } else {
    Yx[bo0] = yr0;
    Yx[bo1] = yr1;
  }
  if (k >= 1) {
    Y2T[(size_t)bo0 * 512 + 255 + k] = yi0;
    Y2T[(size_t)bo1 * 512 + 255 + k] = yi1;
  }
}

// GEMM2: out[b][n][o] = Gm[n][:] . Y2T[bo][:]  + cos(2 pi n/16) * Yx[bo]
__global__ __launch_bounds__(256) void gemm2_kernel(const __hip_bfloat16* __restrict__ Gm,
                                                    const __hip_bfloat16* __restrict__ Y2T,
                                                    const __hip_bfloat16* __restrict__ Yx,
                                                    float* __restrict__ out) {
  __shared__ __hip_bfloat16 As[128 * 64];
  __shared__ __hip_bfloat16 Bs[128 * 64];
  int n0 = blockIdx.x * 128;   // bo
  int m0 = blockIdx.y * 128;   // n (time)
  f32x4 acc[4][4];
#pragma unroll
  for (int m = 0; m < 4; ++m)
#pragma unroll
    for (int n = 0; n < 4; ++n)
#pragma unroll
      for (int r = 0; r < 4; ++r) acc[m][n][r] = 0.f;

  gemm_core(Gm, 512, m0, Y2T, 512, n0, 0, 8, As, Bs, acc);

  const int lane = threadIdx.x & 63;
  const int wv   = threadIdx.x >> 6;
  const int wr   = (wv >> 1) * 64, wc = (wv & 1) * 64;
  const int fr   = lane & 15, fq = lane >> 4;
  float yx[4];
#pragma unroll
  for (int n = 0; n < 4; ++n)
    yx[n] = __bfloat162float(Yx[n0 + wc + n * 16 + fr]);
#pragma unroll
  for (int m = 0; m < 4; ++m)
#pragma unroll
    for (int j = 0; j < 4; ++j) {
      int row = m0 + wr + m * 16 + fq * 4 + j;   // n index
      float g = cos_rev((float)(row & 15) * INV16);
#pragma unroll
      for (int n = 0; n < 4; ++n) {
        int col = n0 + wc + n * 16 + fr;         // bo index
        int b = col >> 6, o = col & 63;
        out[((size_t)b * 4096 + row) * 64 + o] = acc[m][n][j] + g * yx[n];
      }
    }
}

// ---------------------------------------------------------------------------
extern "C" void kernel_launch(void* const* d_in, const int* in_sizes, int n_in,
                              void* d_out, int out_size, void* d_ws, size_t ws_size,
                              hipStream_t stream) {
  const float* x  = (const float*)d_in[0];   // (32,4096,64)
  const float* te = (const float*)d_in[1];   // (32,256)
  const float* wr = (const float*)d_in[2];   // (257,64,64)
  const float* wi = (const float*)d_in[3];
  const float* dr = (const float*)d_in[4];   // (256,257)
  const float* di = (const float*)d_in[5];
  float* out = (float*)d_out;

  char* p = (char*)d_ws;
  auto alloc = [&](size_t bytes) -> char* {
    char* r = p;
    p += (bytes + 255) & ~(size_t)255;
    return r;
  };
  __hip_bfloat16* F2  = (__hip_bfloat16*)alloc(512ull * 4096 * 2);
  __hip_bfloat16* Gm  = (__hip_bfloat16*)alloc(4096ull * 512 * 2);
  __hip_bfloat16* X2T = (__hip_bfloat16*)alloc(2048ull * 4096 * 2);
  float* sigma = (float*)alloc(16 * 2048 * 4);
  float* Sr = (float*)alloc(32 * 257 * 4);
  float* Si = (float*)alloc(32 * 257 * 4);
  __hip_bfloat16* Y2T = (__hip_bfloat16*)alloc(2048ull * 512 * 2);
  __hip_bfloat16* Yx  = (__hip_bfloat16*)alloc(2048 * 2);
  size_t fixed = (size_t)(p - (char*)d_ws);

  int splitk = 1;
  if (ws_size >= fixed + 8ull * 512 * 2048 * 2)      splitk = 8;
  else if (ws_size >= fixed + 4ull * 512 * 2048 * 2) splitk = 4;
  else if (ws_size >= fixed + 2ull * 512 * 2048 * 2) splitk = 2;
  __hip_bfloat16* C1 = (__hip_bfloat16*)alloc((size_t)splitk * 512 * 2048 * 2);
  int kchunk = 4096 / splitk;

  hipMemsetAsync(sigma, 0, 16 * 2048 * 4, stream);
  prep_kernel<<<14368, 256, 0, stream>>>(F2, Gm, te, dr, di, Sr, Si, x, X2T, sigma);
  gemm1_kernel<<<dim3(16, 4, splitk), 256, 0, stream>>>(F2, X2T, C1, kchunk);
  mix_kernel<<<dim3(257, 4), 256, 0, stream>>>(C1, sigma, wr, wi, Sr, Si, Y2T, Yx, splitk);
  gemm2_kernel<<<dim3(16, 32), 256, 0, stream>>>(Gm, Y2T, Yx, out);
}

// Round 5
// 94.471 us; speedup vs baseline: 1.4234x; 1.1742x over previous
//
#include <hip/hip_runtime.h>
#include <hip/hip_bf16.h>

typedef short short8 __attribute__((ext_vector_type(8)));
typedef float f32x4 __attribute__((ext_vector_type(4)));
typedef const void __attribute__((address_space(1))) as1_void;
typedef void __attribute__((address_space(3))) as3_void;

// hardware trig: input in revolutions (D = sin/cos(S0 * 2pi)), already in [0,1)
__device__ __forceinline__ float sin_rev(float r) {
  float o; asm("v_sin_f32 %0, %1" : "=v"(o) : "v"(r)); return o;
}
__device__ __forceinline__ float cos_rev(float r) {
  float o; asm("v_cos_f32 %0, %1" : "=v"(o) : "v"(r)); return o;
}

#define INV4096 0.000244140625f
#define INV16   0.0625f

// ---------------------------------------------------------------------------
// prep_kernel, grid = 3104 blocks x 256 thr, range-partitioned roles:
//   [0, 512)      F2 [512][4096] bf16: row=bid; rows 0..255 = cos m, 256..511 = -sin (m=row-255)
//                 (16 elems/thread, short8 stores)
//   [512, 1024)   Gm [4096][512] bf16: 8 n-rows per block; cols 0..255 cos k, 256..511 -sin k=col-255
//   [1024, 1056)  S[b][m] = (t_emb@dense_r + i t_emb@dense_i) * c_m/4096
//   [1056, 3104)  transpose x (f32 [32][4096][64]) -> X2T bf16 [2048][4096] (coalesced
//                 128B row-chunks) + Xr256p[b][nt][i] = sum_r cos(2pi r/16) x[n0+r][i]
// ---------------------------------------------------------------------------
__global__ __launch_bounds__(256) void prep_kernel(__hip_bfloat16* __restrict__ F2,
                                                   __hip_bfloat16* __restrict__ Gm,
                                                   const float* __restrict__ t_emb,
                                                   const float* __restrict__ dr,
                                                   const float* __restrict__ di,
                                                   float* __restrict__ Sr,
                                                   float* __restrict__ Si,
                                                   const float* __restrict__ x,
                                                   __hip_bfloat16* __restrict__ X2T,
                                                   float* __restrict__ Xr256p) {
  const int bid = blockIdx.x;
  const int tid = threadIdx.x;
  __shared__ float te[256];
  __shared__ float tile[64][65];
  __shared__ float red[4][64];

  if (bid < 512) {
    // F2 row = bid (4096 elems = exactly one row)
    const int row = bid;
    const int m   = (row < 256) ? row : (row - 255);
    const bool is_cos = (row < 256);
#pragma unroll
    for (int it = 0; it < 2; ++it) {
      int n0 = it * 2048 + tid * 8;
      union { short8 v; unsigned short u[8]; } pk;
#pragma unroll
      for (int j = 0; j < 8; ++j) {
        int ph = (m * (n0 + j)) & 4095;
        float v = is_cos ?  cos_rev((float)ph * INV4096)
                         : -sin_rev((float)ph * INV4096);
        __hip_bfloat16 h = __float2bfloat16(v);
        pk.u[j] = *(unsigned short*)&h;
      }
      *(short8*)&F2[(size_t)row * 4096 + n0] = pk.v;
    }
  } else if (bid < 1024) {
    // Gm: 8 n-rows per block
    const int nb = (bid - 512) * 8;
#pragma unroll
    for (int it = 0; it < 2; ++it) {
      int e  = it * 2048 + tid * 8;     // 0..4095
      int n  = nb + (e >> 9);
      int k0 = e & 511;
      union { short8 v; unsigned short u[8]; } pk;
#pragma unroll
      for (int j = 0; j < 8; ++j) {
        int kk = k0 + j;
        int m  = (kk < 256) ? kk : (kk - 255);
        int ph = (m * n) & 4095;
        float v = (kk < 256) ?  cos_rev((float)ph * INV4096)
                             : -sin_rev((float)ph * INV4096);
        __hip_bfloat16 h = __float2bfloat16(v);
        pk.u[j] = *(unsigned short*)&h;
      }
      *(short8*)&Gm[(size_t)n * 512 + k0] = pk.v;
    }
  } else if (bid < 1056) {
    int b = bid - 1024;   // 0..31
    te[tid] = t_emb[b * 256 + tid];
    __syncthreads();
    for (int m = tid; m < 257; m += 256) {
      float ar = 0.f, ai = 0.f;
      for (int t = 0; t < 256; ++t) {
        float e = te[t];
        ar += e * dr[t * 257 + m];
        ai += e * di[t * 257 + m];
      }
      float c = (m == 0 ? 1.0f : 2.0f) * (1.0f / 4096.0f);
      Sr[b * 257 + m] = ar * c;
      Si[b * 257 + m] = ai * c;
    }
  } else {
    int idx = bid - 1056;         // 0..2047
    int nt = idx & 63;            // n-tile
    int b  = idx >> 6;            // batch
    int n0 = nt * 64;
#pragma unroll
    for (int it = 0; it < 4; ++it) {
      int c = it * 256 + tid;     // 0..1023 float4 chunks
      int r = c >> 4, i4 = (c & 15) * 4;
      float4 v = *(const float4*)&x[((size_t)b * 4096 + n0 + r) * 64 + i4];
      tile[r][i4 + 0] = v.x; tile[r][i4 + 1] = v.y;
      tile[r][i4 + 2] = v.z; tile[r][i4 + 3] = v.w;
    }
    __syncthreads();
    // coalesced transposed write: 8 lanes/row -> 128B contiguous chunks
#pragma unroll
    for (int it = 0; it < 2; ++it) {
      int c  = it * 256 + tid;    // 0..511
      int i  = c >> 3;            // 0..63
      int ch = c & 7;             // 0..7 (8-col chunk)
      union { short8 v; unsigned short u[8]; } pk;
#pragma unroll
      for (int j = 0; j < 8; ++j) {
        __hip_bfloat16 h = __float2bfloat16(tile[ch * 8 + j][i]);
        pk.u[j] = *(unsigned short*)&h;
      }
      *(short8*)&X2T[((size_t)b * 64 + i) * 4096 + n0 + ch * 8] = pk.v;
    }
    // Xr256 partial: sum_r cos(2pi r/16) * tile[r][i]   (r mod 16 periodic)
    {
      int i = tid & 63, g = tid >> 6;   // g: 16-row group
      float acc = 0.f;
#pragma unroll
      for (int j = 0; j < 16; ++j)
        acc += cos_rev((float)j * INV16) * tile[g * 16 + j][i];
      red[g][i] = acc;
    }
    __syncthreads();
    if (tid < 64) {
      Xr256p[((size_t)b * 64 + nt) * 64 + tid] =
          red[0][tid] + red[1][tid] + red[2][tid] + red[3][tid];
    }
  }
}

// ---------------------------------------------------------------------------
// Shared MFMA GEMM core (m97 structure, T2 pre-swizzled-source chunk swizzle)
// ---------------------------------------------------------------------------
__device__ __forceinline__ void gemm_core(const __hip_bfloat16* __restrict__ A, int lda, int m0,
                                          const __hip_bfloat16* __restrict__ B, int ldb, int n0,
                                          int k0, int ksteps,
                                          __hip_bfloat16* As, __hip_bfloat16* Bs,
                                          f32x4 acc[4][4]) {
  const int tid  = threadIdx.x;
  const int lane = tid & 63;
  const int wv   = tid >> 6;
  const int wr   = (wv >> 1) * 64;
  const int wc   = (wv & 1) * 64;
  const int fr   = lane & 15;
  const int fq   = lane >> 4;

  for (int ks = 0; ks < ksteps; ++ks) {
    int kt = k0 + ks * 64;
#pragma unroll
    for (int j = 0; j < 4; ++j) {
      int c   = j * 256 + tid;           // 0..1023
      int row = c >> 3;
      int chg = (c & 7) ^ (row & 7);     // swizzled source chunk
      const __hip_bfloat16* ga = A + (size_t)(m0 + row) * lda + kt + chg * 8;
      const __hip_bfloat16* gb = B + (size_t)(n0 + row) * ldb + kt + chg * 8;
      __hip_bfloat16* la = As + (size_t)(j * 256 + (tid & 192)) * 8;
      __hip_bfloat16* lb = Bs + (size_t)(j * 256 + (tid & 192)) * 8;
      __builtin_amdgcn_global_load_lds((as1_void*)ga, (as3_void*)la, 16, 0, 0);
      __builtin_amdgcn_global_load_lds((as1_void*)gb, (as3_void*)lb, 16, 0, 0);
    }
    __syncthreads();
#pragma unroll
    for (int kk = 0; kk < 2; ++kk) {
      short8 av[4], bv[4];
#pragma unroll
      for (int m = 0; m < 4; ++m) {
        int row  = wr + m * 16 + fr;
        int slot = (fq + kk * 4) ^ (row & 7);
        av[m] = *(const short8*)(As + row * 64 + slot * 8);
      }
#pragma unroll
      for (int n = 0; n < 4; ++n) {
        int row  = wc + n * 16 + fr;
        int slot = (fq + kk * 4) ^ (row & 7);
        bv[n] = *(const short8*)(Bs + row * 64 + slot * 8);
      }
#pragma unroll
      for (int m = 0; m < 4; ++m)
#pragma unroll
        for (int n = 0; n < 4; ++n)
          acc[m][n] = __builtin_amdgcn_mfma_f32_16x16x32_bf16(av[m], bv[n], acc[m][n], 0, 0, 0);
    }
    __syncthreads();
  }
}

// GEMM1: C1[z][row][bi] (bf16 split-K partials) = F2 @ X2T^T   (512 rows, all live)
__global__ __launch_bounds__(256) void gemm1_kernel(const __hip_bfloat16* __restrict__ F2,
                                                    const __hip_bfloat16* __restrict__ X2T,
                                                    __hip_bfloat16* __restrict__ C1, int kchunk) {
  __shared__ __hip_bfloat16 As[128 * 64];
  __shared__ __hip_bfloat16 Bs[128 * 64];
  int n0 = blockIdx.x * 128;
  int m0 = blockIdx.y * 128;
  int k0 = blockIdx.z * kchunk;
  f32x4 acc[4][4];
#pragma unroll
  for (int m = 0; m < 4; ++m)
#pragma unroll
    for (int n = 0; n < 4; ++n)
#pragma unroll
      for (int r = 0; r < 4; ++r) acc[m][n][r] = 0.f;

  gemm_core(F2, 4096, m0, X2T, 4096, n0, k0, kchunk >> 6, As, Bs, acc);

  const int lane = threadIdx.x & 63;
  const int wv   = threadIdx.x >> 6;
  const int wr   = (wv >> 1) * 64, wc = (wv & 1) * 64;
  const int fr   = lane & 15, fq = lane >> 4;
  __hip_bfloat16* P = C1 + (size_t)blockIdx.z * (512 * 2048);
#pragma unroll
  for (int m = 0; m < 4; ++m)
#pragma unroll
    for (int n = 0; n < 4; ++n)
#pragma unroll
      for (int j = 0; j < 4; ++j) {
        int row = m0 + wr + m * 16 + fq * 4 + j;
        int col = n0 + wc + n * 16 + fr;
        P[(size_t)row * 2048 + col] = __float2bfloat16(acc[m][n][j]);
      }
}

// ---------------------------------------------------------------------------
// Mode mix (fused split-K reduce, direct transposed output):
// per (k, quadrant q): xr = sum_z C1[z][k] (k<256) or sum_nt Xr256p (k=256)
//                      xi = sum_z C1[z][255+k] (k>=1) or 0 (k=0)
//   Y[b][o] = ((x . W) * S)  ->  Y2T[bo][k] (k<256) / Yx[bo] (k=256);
//                                Y2T[bo][255+k] (k>=1)
// ---------------------------------------------------------------------------
__global__ __launch_bounds__(256) void mix_kernel(const __hip_bfloat16* __restrict__ C1,
                                                  const float* __restrict__ Xr256p,
                                                  const float* __restrict__ Wr,
                                                  const float* __restrict__ Wi,
                                                  const float* __restrict__ Sr,
                                                  const float* __restrict__ Si,
                                                  __hip_bfloat16* __restrict__ Y2T,
                                                  __hip_bfloat16* __restrict__ Yx,
                                                  int splitk) {
  const int k = blockIdx.x;   // 0..256
  const int q = blockIdx.y;   // 0..3 (batches q*8 .. q*8+7)
  const int tid = threadIdx.x;
  __shared__ float wlr[4096];
  __shared__ float wli[4096];
  __shared__ float xs[1024];   // [0..511]=real, [512..1023]=imag; col = bl*64+i

  // stage weights for mode k (32 KB)
  const float* wrg = Wr + (size_t)k * 4096;
  const float* wig = Wi + (size_t)k * 4096;
  for (int c = tid; c < 1024; c += 256) {
    *(float4*)&wlr[c * 4] = *(const float4*)&wrg[c * 4];
    *(float4*)&wli[c * 4] = *(const float4*)&wig[c * 4];
  }
  // fused split-K reduce of this block's 512-column segment
  const size_t PST = 512ull * 2048;
  for (int idx = tid; idx < 1024; idx += 256) {
    int part = idx >> 9;
    int c    = idx & 511;
    float s = 0.f;
    if (part == 0) {
      if (k < 256) {
        const __hip_bfloat16* src = C1 + (size_t)k * 2048 + q * 512 + c;
        for (int z = 0; z < splitk; ++z) s += __bfloat162float(src[(size_t)z * PST]);
      } else {
        int bi = q * 512 + c;
        const float* sp = Xr256p + (size_t)(bi >> 6) * 4096 + (bi & 63);
#pragma unroll 8
        for (int nt = 0; nt < 64; ++nt) s += sp[nt * 64];
      }
    } else if (k > 0) {
      const __hip_bfloat16* src = C1 + (size_t)(255 + k) * 2048 + q * 512 + c;
      for (int z = 0; z < splitk; ++z) s += __bfloat162float(src[(size_t)z * PST]);
    }
    xs[idx] = s;
  }
  __syncthreads();

  const int o  = tid & 63;
  const int jj = tid >> 6;          // 0..3
  const int bl0 = jj * 2, bl1 = jj * 2 + 1;
  float pr0 = 0.f, pi0 = 0.f, pr1 = 0.f, pi1 = 0.f;
#pragma unroll 8
  for (int i = 0; i < 64; ++i) {
    float wrv = wlr[i * 64 + o];
    float wiv = wli[i * 64 + o];
    float xr0 = xs[bl0 * 64 + i], xi0 = xs[512 + bl0 * 64 + i];
    float xr1 = xs[bl1 * 64 + i], xi1 = xs[512 + bl1 * 64 + i];
    pr0 += xr0 * wrv - xi0 * wiv;
    pi0 += xr0 * wiv + xi0 * wrv;
    pr1 += xr1 * wrv - xi1 * wiv;
    pi1 += xr1 * wiv + xi1 * wrv;
  }
  int b0 = q * 8 + bl0, b1 = q * 8 + bl1;
  float sr0 = Sr[b0 * 257 + k], si0 = Si[b0 * 257 + k];
  float sr1 = Sr[b1 * 257 + k], si1 = Si[b1 * 257 + k];
  int bo0 = b0 * 64 + o, bo1 = b1 * 64 + o;
  __hip_bfloat16 yr0 = __float2bfloat16(pr0 * sr0 - pi0 * si0);
  __hip_bfloat16 yi0 = __float2bfloat16(pr0 * si0 + pi0 * sr0);
  __hip_bfloat16 yr1 = __float2bfloat16(pr1 * sr1 - pi1 * si1);
  __hip_bfloat16 yi1 = __float2bfloat16(pr1 * si1 + pi1 * sr1);
  if (k < 256) {
    Y2T[(size_t)bo0 * 512 + k] = yr0;
    Y2T[(size_t)bo1 * 512 + k] = yr1;
  } else {
    Yx[bo0] = yr0;
    Yx[bo1] = yr1;
  }
  if (k >= 1) {
    Y2T[(size_t)bo0 * 512 + 255 + k] = yi0;
    Y2T[(size_t)bo1 * 512 + 255 + k] = yi1;
  }
}

// GEMM2: out[b][n][o] = Gm[n][:] . Y2T[bo][:]  + cos(2 pi n/16) * Yx[bo]
__global__ __launch_bounds__(256) void gemm2_kernel(const __hip_bfloat16* __restrict__ Gm,
                                                    const __hip_bfloat16* __restrict__ Y2T,
                                                    const __hip_bfloat16* __restrict__ Yx,
                                                    float* __restrict__ out) {
  __shared__ __hip_bfloat16 As[128 * 64];
  __shared__ __hip_bfloat16 Bs[128 * 64];
  int n0 = blockIdx.x * 128;   // bo
  int m0 = blockIdx.y * 128;   // n (time)
  f32x4 acc[4][4];
#pragma unroll
  for (int m = 0; m < 4; ++m)
#pragma unroll
    for (int n = 0; n < 4; ++n)
#pragma unroll
      for (int r = 0; r < 4; ++r) acc[m][n][r] = 0.f;

  gemm_core(Gm, 512, m0, Y2T, 512, n0, 0, 8, As, Bs, acc);

  const int lane = threadIdx.x & 63;
  const int wv   = threadIdx.x >> 6;
  const int wr   = (wv >> 1) * 64, wc = (wv & 1) * 64;
  const int fr   = lane & 15, fq = lane >> 4;
  float yx[4];
#pragma unroll
  for (int n = 0; n < 4; ++n)
    yx[n] = __bfloat162float(Yx[n0 + wc + n * 16 + fr]);
#pragma unroll
  for (int m = 0; m < 4; ++m)
#pragma unroll
    for (int j = 0; j < 4; ++j) {
      int row = m0 + wr + m * 16 + fq * 4 + j;   // n index
      float g = cos_rev((float)(row & 15) * INV16);
#pragma unroll
      for (int n = 0; n < 4; ++n) {
        int col = n0 + wc + n * 16 + fr;         // bo index
        int b = col >> 6, o = col & 63;
        out[((size_t)b * 4096 + row) * 64 + o] = acc[m][n][j] + g * yx[n];
      }
    }
}

// ---------------------------------------------------------------------------
extern "C" void kernel_launch(void* const* d_in, const int* in_sizes, int n_in,
                              void* d_out, int out_size, void* d_ws, size_t ws_size,
                              hipStream_t stream) {
  const float* x  = (const float*)d_in[0];   // (32,4096,64)
  const float* te = (const float*)d_in[1];   // (32,256)
  const float* wr = (const float*)d_in[2];   // (257,64,64)
  const float* wi = (const float*)d_in[3];
  const float* dr = (const float*)d_in[4];   // (256,257)
  const float* di = (const float*)d_in[5];
  float* out = (float*)d_out;

  char* p = (char*)d_ws;
  auto alloc = [&](size_t bytes) -> char* {
    char* r = p;
    p += (bytes + 255) & ~(size_t)255;
    return r;
  };
  __hip_bfloat16* F2  = (__hip_bfloat16*)alloc(512ull * 4096 * 2);
  __hip_bfloat16* Gm  = (__hip_bfloat16*)alloc(4096ull * 512 * 2);
  __hip_bfloat16* X2T = (__hip_bfloat16*)alloc(2048ull * 4096 * 2);
  float* Xr256p = (float*)alloc(32ull * 64 * 64 * 4);   // [b][nt][i]
  float* Sr = (float*)alloc(32 * 257 * 4);
  float* Si = (float*)alloc(32 * 257 * 4);
  __hip_bfloat16* Y2T = (__hip_bfloat16*)alloc(2048ull * 512 * 2);
  __hip_bfloat16* Yx  = (__hip_bfloat16*)alloc(2048 * 2);
  size_t fixed = (size_t)(p - (char*)d_ws);

  int splitk = 1;
  if (ws_size >= fixed + 8ull * 512 * 2048 * 2)      splitk = 8;
  else if (ws_size >= fixed + 4ull * 512 * 2048 * 2) splitk = 4;
  else if (ws_size >= fixed + 2ull * 512 * 2048 * 2) splitk = 2;
  __hip_bfloat16* C1 = (__hip_bfloat16*)alloc((size_t)splitk * 512 * 2048 * 2);
  int kchunk = 4096 / splitk;

  prep_kernel<<<3104, 256, 0, stream>>>(F2, Gm, te, dr, di, Sr, Si, x, X2T, Xr256p);
  gemm1_kernel<<<dim3(16, 4, splitk), 256, 0, stream>>>(F2, X2T, C1, kchunk);
  mix_kernel<<<dim3(257, 4), 256, 0, stream>>>(C1, Xr256p, wr, wi, Sr, Si, Y2T, Yx, splitk);
  gemm2_kernel<<<dim3(16, 32), 256, 0, stream>>>(Gm, Y2T, Yx, out);
}

// Round 6
// 90.871 us; speedup vs baseline: 1.4798x; 1.0396x over previous
//
#include <hip/hip_runtime.h>
#include <hip/hip_bf16.h>

typedef short short8 __attribute__((ext_vector_type(8)));
typedef float f32x4 __attribute__((ext_vector_type(4)));
typedef const void __attribute__((address_space(1))) as1_void;
typedef void __attribute__((address_space(3))) as3_void;

// hardware trig: input in revolutions (D = sin/cos(S0 * 2pi)), already in [0,1)
__device__ __forceinline__ float sin_rev(float r) {
  float o; asm("v_sin_f32 %0, %1" : "=v"(o) : "v"(r)); return o;
}
__device__ __forceinline__ float cos_rev(float r) {
  float o; asm("v_cos_f32 %0, %1" : "=v"(o) : "v"(r)); return o;
}

#define INV4096 0.000244140625f
#define INV16   0.0625f

// ---------------------------------------------------------------------------
// prep_kernel, grid = 3104 blocks x 256 thr, range-partitioned roles:
//   [0, 512)      F2 [512][4096] bf16: row=bid; rows 0..255 = cos m, 256..511 = -sin (m=row-255)
//   [512, 1024)   Gm [4096][512] bf16: 8 n-rows per block
//   [1024, 1056)  S[b][m] = (t_emb@dense_r + i t_emb@dense_i) * c_m/4096
//   [1056, 3104)  transpose x -> X2T bf16 [2048][4096] + Xr256p partials
// ---------------------------------------------------------------------------
__global__ __launch_bounds__(256) void prep_kernel(__hip_bfloat16* __restrict__ F2,
                                                   __hip_bfloat16* __restrict__ Gm,
                                                   const float* __restrict__ t_emb,
                                                   const float* __restrict__ dr,
                                                   const float* __restrict__ di,
                                                   float* __restrict__ Sr,
                                                   float* __restrict__ Si,
                                                   const float* __restrict__ x,
                                                   __hip_bfloat16* __restrict__ X2T,
                                                   float* __restrict__ Xr256p) {
  const int bid = blockIdx.x;
  const int tid = threadIdx.x;
  __shared__ float te[256];
  __shared__ float tile[64][65];
  __shared__ float red[4][64];

  if (bid < 512) {
    const int row = bid;
    const int m   = (row < 256) ? row : (row - 255);
    const bool is_cos = (row < 256);
#pragma unroll
    for (int it = 0; it < 2; ++it) {
      int n0 = it * 2048 + tid * 8;
      union { short8 v; unsigned short u[8]; } pk;
#pragma unroll
      for (int j = 0; j < 8; ++j) {
        int ph = (m * (n0 + j)) & 4095;
        float v = is_cos ?  cos_rev((float)ph * INV4096)
                         : -sin_rev((float)ph * INV4096);
        __hip_bfloat16 h = __float2bfloat16(v);
        pk.u[j] = *(unsigned short*)&h;
      }
      *(short8*)&F2[(size_t)row * 4096 + n0] = pk.v;
    }
  } else if (bid < 1024) {
    const int nb = (bid - 512) * 8;
#pragma unroll
    for (int it = 0; it < 2; ++it) {
      int e  = it * 2048 + tid * 8;     // 0..4095
      int n  = nb + (e >> 9);
      int k0 = e & 511;
      union { short8 v; unsigned short u[8]; } pk;
#pragma unroll
      for (int j = 0; j < 8; ++j) {
        int kk = k0 + j;
        int m  = (kk < 256) ? kk : (kk - 255);
        int ph = (m * n) & 4095;
        float v = (kk < 256) ?  cos_rev((float)ph * INV4096)
                             : -sin_rev((float)ph * INV4096);
        __hip_bfloat16 h = __float2bfloat16(v);
        pk.u[j] = *(unsigned short*)&h;
      }
      *(short8*)&Gm[(size_t)n * 512 + k0] = pk.v;
    }
  } else if (bid < 1056) {
    int b = bid - 1024;   // 0..31
    te[tid] = t_emb[b * 256 + tid];
    __syncthreads();
    for (int m = tid; m < 257; m += 256) {
      float ar = 0.f, ai = 0.f;
      for (int t = 0; t < 256; ++t) {
        float e = te[t];
        ar += e * dr[t * 257 + m];
        ai += e * di[t * 257 + m];
      }
      float c = (m == 0 ? 1.0f : 2.0f) * (1.0f / 4096.0f);
      Sr[b * 257 + m] = ar * c;
      Si[b * 257 + m] = ai * c;
    }
  } else {
    int idx = bid - 1056;         // 0..2047
    int nt = idx & 63;            // n-tile
    int b  = idx >> 6;            // batch
    int n0 = nt * 64;
#pragma unroll
    for (int it = 0; it < 4; ++it) {
      int c = it * 256 + tid;     // 0..1023 float4 chunks
      int r = c >> 4, i4 = (c & 15) * 4;
      float4 v = *(const float4*)&x[((size_t)b * 4096 + n0 + r) * 64 + i4];
      tile[r][i4 + 0] = v.x; tile[r][i4 + 1] = v.y;
      tile[r][i4 + 2] = v.z; tile[r][i4 + 3] = v.w;
    }
    __syncthreads();
    // coalesced transposed write: 8 lanes/row -> 128B contiguous chunks
#pragma unroll
    for (int it = 0; it < 2; ++it) {
      int c  = it * 256 + tid;    // 0..511
      int i  = c >> 3;            // 0..63
      int ch = c & 7;             // 0..7 (8-col chunk)
      union { short8 v; unsigned short u[8]; } pk;
#pragma unroll
      for (int j = 0; j < 8; ++j) {
        __hip_bfloat16 h = __float2bfloat16(tile[ch * 8 + j][i]);
        pk.u[j] = *(unsigned short*)&h;
      }
      *(short8*)&X2T[((size_t)b * 64 + i) * 4096 + n0 + ch * 8] = pk.v;
    }
    // Xr256 partial: sum_r cos(2pi r/16) * tile[r][i]   (r mod 16 periodic)
    {
      int i = tid & 63, g = tid >> 6;   // g: 16-row group
      float acc = 0.f;
#pragma unroll
      for (int j = 0; j < 16; ++j)
        acc += cos_rev((float)j * INV16) * tile[g * 16 + j][i];
      red[g][i] = acc;
    }
    __syncthreads();
    if (tid < 64) {
      Xr256p[((size_t)b * 64 + nt) * 64 + tid] =
          red[0][tid] + red[1][tid] + red[2][tid] + red[3][tid];
    }
  }
}

// ---------------------------------------------------------------------------
// MFMA GEMM core, T3-minimal 2-phase: double-buffered LDS, next K-step's
// global_load_lds issued BEFORE current step's ds_read+MFMA; single
// __syncthreads (with its compiler-emitted vmcnt(0) drain) per K-step.
// T2 chunk-XOR swizzle via pre-swizzled global source (both-sides).
// ---------------------------------------------------------------------------
__device__ __forceinline__ void stage_tile(const __hip_bfloat16* __restrict__ A, int lda, int m0,
                                           const __hip_bfloat16* __restrict__ B, int ldb, int n0,
                                           int kt, __hip_bfloat16* As, __hip_bfloat16* Bs,
                                           int tid) {
#pragma unroll
  for (int j = 0; j < 4; ++j) {
    int c   = j * 256 + tid;           // 0..1023
    int row = c >> 3;
    int chg = (c & 7) ^ (row & 7);     // swizzled source chunk
    const __hip_bfloat16* ga = A + (size_t)(m0 + row) * lda + kt + chg * 8;
    const __hip_bfloat16* gb = B + (size_t)(n0 + row) * ldb + kt + chg * 8;
    __hip_bfloat16* la = As + (size_t)(j * 256 + (tid & 192)) * 8;
    __hip_bfloat16* lb = Bs + (size_t)(j * 256 + (tid & 192)) * 8;
    __builtin_amdgcn_global_load_lds((as1_void*)ga, (as3_void*)la, 16, 0, 0);
    __builtin_amdgcn_global_load_lds((as1_void*)gb, (as3_void*)lb, 16, 0, 0);
  }
}

__device__ __forceinline__ void compute_step(const __hip_bfloat16* As, const __hip_bfloat16* Bs,
                                             int wr, int wc, int fr, int fq,
                                             f32x4 acc[4][4]) {
#pragma unroll
  for (int kk = 0; kk < 2; ++kk) {
    short8 av[4], bv[4];
#pragma unroll
    for (int m = 0; m < 4; ++m) {
      int row  = wr + m * 16 + fr;
      int slot = (fq + kk * 4) ^ (row & 7);
      av[m] = *(const short8*)(As + row * 64 + slot * 8);
    }
#pragma unroll
    for (int n = 0; n < 4; ++n) {
      int row  = wc + n * 16 + fr;
      int slot = (fq + kk * 4) ^ (row & 7);
      bv[n] = *(const short8*)(Bs + row * 64 + slot * 8);
    }
#pragma unroll
    for (int m = 0; m < 4; ++m)
#pragma unroll
      for (int n = 0; n < 4; ++n)
        acc[m][n] = __builtin_amdgcn_mfma_f32_16x16x32_bf16(av[m], bv[n], acc[m][n], 0, 0, 0);
  }
}

__device__ __forceinline__ void gemm_core(const __hip_bfloat16* __restrict__ A, int lda, int m0,
                                          const __hip_bfloat16* __restrict__ B, int ldb, int n0,
                                          int k0, int ksteps,
                                          __hip_bfloat16* As0, __hip_bfloat16* Bs0,
                                          __hip_bfloat16* As1, __hip_bfloat16* Bs1,
                                          f32x4 acc[4][4]) {
  const int tid  = threadIdx.x;
  const int lane = tid & 63;
  const int wv   = tid >> 6;
  const int wr   = (wv >> 1) * 64;
  const int wc   = (wv & 1) * 64;
  const int fr   = lane & 15;
  const int fq   = lane >> 4;

  // prologue: fill buffer 0
  stage_tile(A, lda, m0, B, ldb, n0, k0, As0, Bs0, tid);
  __syncthreads();   // drains vmcnt(0)

  __hip_bfloat16 *Ac = As0, *Bc = Bs0, *An = As1, *Bn = Bs1;
  for (int ks = 0; ks < ksteps; ++ks) {
    if (ks + 1 < ksteps)   // issue next tile's loads FIRST (overlap with MFMA below)
      stage_tile(A, lda, m0, B, ldb, n0, k0 + (ks + 1) * 64, An, Bn, tid);
    compute_step(Ac, Bc, wr, wc, fr, fq, acc);
    __syncthreads();       // all waves done reading Ac/Bc; next-tile loads drained
    __hip_bfloat16* t;
    t = Ac; Ac = An; An = t;
    t = Bc; Bc = Bn; Bn = t;
  }
}

// GEMM1: C1[z][row][bi] (bf16 split-K partials) = F2 @ X2T^T   (512 rows, all live)
__global__ __launch_bounds__(256) void gemm1_kernel(const __hip_bfloat16* __restrict__ F2,
                                                    const __hip_bfloat16* __restrict__ X2T,
                                                    __hip_bfloat16* __restrict__ C1, int kchunk) {
  __shared__ __hip_bfloat16 As0[128 * 64];
  __shared__ __hip_bfloat16 Bs0[128 * 64];
  __shared__ __hip_bfloat16 As1[128 * 64];
  __shared__ __hip_bfloat16 Bs1[128 * 64];
  int n0 = blockIdx.x * 128;
  int m0 = blockIdx.y * 128;
  int k0 = blockIdx.z * kchunk;
  f32x4 acc[4][4];
#pragma unroll
  for (int m = 0; m < 4; ++m)
#pragma unroll
    for (int n = 0; n < 4; ++n)
#pragma unroll
      for (int r = 0; r < 4; ++r) acc[m][n][r] = 0.f;

  gemm_core(F2, 4096, m0, X2T, 4096, n0, k0, kchunk >> 6, As0, Bs0, As1, Bs1, acc);

  const int lane = threadIdx.x & 63;
  const int wv   = threadIdx.x >> 6;
  const int wr   = (wv >> 1) * 64, wc = (wv & 1) * 64;
  const int fr   = lane & 15, fq = lane >> 4;
  __hip_bfloat16* P = C1 + (size_t)blockIdx.z * (512 * 2048);
#pragma unroll
  for (int m = 0; m < 4; ++m)
#pragma unroll
    for (int n = 0; n < 4; ++n)
#pragma unroll
      for (int j = 0; j < 4; ++j) {
        int row = m0 + wr + m * 16 + fq * 4 + j;
        int col = n0 + wc + n * 16 + fr;
        P[(size_t)row * 2048 + col] = __float2bfloat16(acc[m][n][j]);
      }
}

// ---------------------------------------------------------------------------
// Mode mix (fused split-K reduce, direct transposed output)
// ---------------------------------------------------------------------------
__global__ __launch_bounds__(256) void mix_kernel(const __hip_bfloat16* __restrict__ C1,
                                                  const float* __restrict__ Xr256p,
                                                  const float* __restrict__ Wr,
                                                  const float* __restrict__ Wi,
                                                  const float* __restrict__ Sr,
                                                  const float* __restrict__ Si,
                                                  __hip_bfloat16* __restrict__ Y2T,
                                                  __hip_bfloat16* __restrict__ Yx,
                                                  int splitk) {
  const int k = blockIdx.x;   // 0..256
  const int q = blockIdx.y;   // 0..3 (batches q*8 .. q*8+7)
  const int tid = threadIdx.x;
  __shared__ float wlr[4096];
  __shared__ float wli[4096];
  __shared__ float xs[1024];   // [0..511]=real, [512..1023]=imag; col = bl*64+i

  const float* wrg = Wr + (size_t)k * 4096;
  const float* wig = Wi + (size_t)k * 4096;
  for (int c = tid; c < 1024; c += 256) {
    *(float4*)&wlr[c * 4] = *(const float4*)&wrg[c * 4];
    *(float4*)&wli[c * 4] = *(const float4*)&wig[c * 4];
  }
  const size_t PST = 512ull * 2048;
  for (int idx = tid; idx < 1024; idx += 256) {
    int part = idx >> 9;
    int c    = idx & 511;
    float s = 0.f;
    if (part == 0) {
      if (k < 256) {
        const __hip_bfloat16* src = C1 + (size_t)k * 2048 + q * 512 + c;
        for (int z = 0; z < splitk; ++z) s += __bfloat162float(src[(size_t)z * PST]);
      } else {
        int bi = q * 512 + c;
        const float* sp = Xr256p + (size_t)(bi >> 6) * 4096 + (bi & 63);
#pragma unroll 8
        for (int nt = 0; nt < 64; ++nt) s += sp[nt * 64];
      }
    } else if (k > 0) {
      const __hip_bfloat16* src = C1 + (size_t)(255 + k) * 2048 + q * 512 + c;
      for (int z = 0; z < splitk; ++z) s += __bfloat162float(src[(size_t)z * PST]);
    }
    xs[idx] = s;
  }
  __syncthreads();

  const int o  = tid & 63;
  const int jj = tid >> 6;          // 0..3
  const int bl0 = jj * 2, bl1 = jj * 2 + 1;
  float pr0 = 0.f, pi0 = 0.f, pr1 = 0.f, pi1 = 0.f;
#pragma unroll 8
  for (int i = 0; i < 64; ++i) {
    float wrv = wlr[i * 64 + o];
    float wiv = wli[i * 64 + o];
    float xr0 = xs[bl0 * 64 + i], xi0 = xs[512 + bl0 * 64 + i];
    float xr1 = xs[bl1 * 64 + i], xi1 = xs[512 + bl1 * 64 + i];
    pr0 += xr0 * wrv - xi0 * wiv;
    pi0 += xr0 * wiv + xi0 * wrv;
    pr1 += xr1 * wrv - xi1 * wiv;
    pi1 += xr1 * wiv + xi1 * wrv;
  }
  int b0 = q * 8 + bl0, b1 = q * 8 + bl1;
  float sr0 = Sr[b0 * 257 + k], si0 = Si[b0 * 257 + k];
  float sr1 = Sr[b1 * 257 + k], si1 = Si[b1 * 257 + k];
  int bo0 = b0 * 64 + o, bo1 = b1 * 64 + o;
  __hip_bfloat16 yr0 = __float2bfloat16(pr0 * sr0 - pi0 * si0);
  __hip_bfloat16 yi0 = __float2bfloat16(pr0 * si0 + pi0 * sr0);
  __hip_bfloat16 yr1 = __float2bfloat16(pr1 * sr1 - pi1 * si1);
  __hip_bfloat16 yi1 = __float2bfloat16(pr1 * si1 + pi1 * sr1);
  if (k < 256) {
    Y2T[(size_t)bo0 * 512 + k] = yr0;
    Y2T[(size_t)bo1 * 512 + k] = yr1;
  } else {
    Yx[bo0] = yr0;
    Yx[bo1] = yr1;
  }
  if (k >= 1) {
    Y2T[(size_t)bo0 * 512 + 255 + k] = yi0;
    Y2T[(size_t)bo1 * 512 + 255 + k] = yi1;
  }
}

// GEMM2: out[b][n][o] = Gm[n][:] . Y2T[bo][:]  + cos(2 pi n/16) * Yx[bo]
__global__ __launch_bounds__(256) void gemm2_kernel(const __hip_bfloat16* __restrict__ Gm,
                                                    const __hip_bfloat16* __restrict__ Y2T,
                                                    const __hip_bfloat16* __restrict__ Yx,
                                                    float* __restrict__ out) {
  __shared__ __hip_bfloat16 As0[128 * 64];
  __shared__ __hip_bfloat16 Bs0[128 * 64];
  __shared__ __hip_bfloat16 As1[128 * 64];
  __shared__ __hip_bfloat16 Bs1[128 * 64];
  int n0 = blockIdx.x * 128;   // bo
  int m0 = blockIdx.y * 128;   // n (time)
  f32x4 acc[4][4];
#pragma unroll
  for (int m = 0; m < 4; ++m)
#pragma unroll
    for (int n = 0; n < 4; ++n)
#pragma unroll
      for (int r = 0; r < 4; ++r) acc[m][n][r] = 0.f;

  gemm_core(Gm, 512, m0, Y2T, 512, n0, 0, 8, As0, Bs0, As1, Bs1, acc);

  const int lane = threadIdx.x & 63;
  const int wv   = threadIdx.x >> 6;
  const int wr   = (wv >> 1) * 64, wc = (wv & 1) * 64;
  const int fr   = lane & 15, fq = lane >> 4;
  float yx[4];
#pragma unroll
  for (int n = 0; n < 4; ++n)
    yx[n] = __bfloat162float(Yx[n0 + wc + n * 16 + fr]);
#pragma unroll
  for (int m = 0; m < 4; ++m)
#pragma unroll
    for (int j = 0; j < 4; ++j) {
      int row = m0 + wr + m * 16 + fq * 4 + j;   // n index
      float g = cos_rev((float)(row & 15) * INV16);
#pragma unroll
      for (int n = 0; n < 4; ++n) {
        int col = n0 + wc + n * 16 + fr;         // bo index
        int b = col >> 6, o = col & 63;
        out[((size_t)b * 4096 + row) * 64 + o] = acc[m][n][j] + g * yx[n];
      }
    }
}

// ---------------------------------------------------------------------------
extern "C" void kernel_launch(void* const* d_in, const int* in_sizes, int n_in,
                              void* d_out, int out_size, void* d_ws, size_t ws_size,
                              hipStream_t stream) {
  const float* x  = (const float*)d_in[0];   // (32,4096,64)
  const float* te = (const float*)d_in[1];   // (32,256)
  const float* wr = (const float*)d_in[2];   // (257,64,64)
  const float* wi = (const float*)d_in[3];
  const float* dr = (const float*)d_in[4];   // (256,257)
  const float* di = (const float*)d_in[5];
  float* out = (float*)d_out;

  char* p = (char*)d_ws;
  auto alloc = [&](size_t bytes) -> char* {
    char* r = p;
    p += (bytes + 255) & ~(size_t)255;
    return r;
  };
  __hip_bfloat16* F2  = (__hip_bfloat16*)alloc(512ull * 4096 * 2);
  __hip_bfloat16* Gm  = (__hip_bfloat16*)alloc(4096ull * 512 * 2);
  __hip_bfloat16* X2T = (__hip_bfloat16*)alloc(2048ull * 4096 * 2);
  float* Xr256p = (float*)alloc(32ull * 64 * 64 * 4);   // [b][nt][i]
  float* Sr = (float*)alloc(32 * 257 * 4);
  float* Si = (float*)alloc(32 * 257 * 4);
  __hip_bfloat16* Y2T = (__hip_bfloat16*)alloc(2048ull * 512 * 2);
  __hip_bfloat16* Yx  = (__hip_bfloat16*)alloc(2048 * 2);
  size_t fixed = (size_t)(p - (char*)d_ws);

  int splitk = 1;
  if (ws_size >= fixed + 8ull * 512 * 2048 * 2)      splitk = 8;
  else if (ws_size >= fixed + 4ull * 512 * 2048 * 2) splitk = 4;
  else if (ws_size >= fixed + 2ull * 512 * 2048 * 2) splitk = 2;
  __hip_bfloat16* C1 = (__hip_bfloat16*)alloc((size_t)splitk * 512 * 2048 * 2);
  int kchunk = 4096 / splitk;

  prep_kernel<<<3104, 256, 0, stream>>>(F2, Gm, te, dr, di, Sr, Si, x, X2T, Xr256p);
  gemm1_kernel<<<dim3(16, 4, splitk), 256, 0, stream>>>(F2, X2T, C1, kchunk);
  mix_kernel<<<dim3(257, 4), 256, 0, stream>>>(C1, Xr256p, wr, wi, Sr, Si, Y2T, Yx, splitk);
  gemm2_kernel<<<dim3(16, 32), 256, 0, stream>>>(Gm, Y2T, Yx, out);
}